// Round 1
// baseline (1283.369 us; speedup 1.0000x reference)
//
#include <hip/hip_runtime.h>
#include <math.h>

#define BB 2
#define LL 4096
#define DD 1024
#define DS 16
#define RK 64
#define MM (BB*LL)        // 8192
#define NC 64             // scan chunks
#define LC (LL/NC)        // 64

// ---------------- LayerNorm: one block per row ----------------
__global__ __launch_bounds__(256)
void ln_kernel(const float* __restrict__ x, const float* __restrict__ gamma,
               const float* __restrict__ beta, float* __restrict__ xn) {
    int row = blockIdx.x;
    int tid = threadIdx.x;
    const float4* xr = (const float4*)(x + (size_t)row * DD);
    float4 v = xr[tid];                       // 256*4 = 1024
    float s = v.x + v.y + v.z + v.w;
    float q = v.x*v.x + v.y*v.y + v.z*v.z + v.w*v.w;
    #pragma unroll
    for (int off = 32; off > 0; off >>= 1) {
        s += __shfl_down(s, off);
        q += __shfl_down(q, off);
    }
    __shared__ float ss[4], qq[4];
    int wv = tid >> 6;
    if ((tid & 63) == 0) { ss[wv] = s; qq[wv] = q; }
    __syncthreads();
    float S = ss[0] + ss[1] + ss[2] + ss[3];
    float Q = qq[0] + qq[1] + qq[2] + qq[3];
    float mu  = S * (1.0f / DD);
    float var = Q * (1.0f / DD) - mu * mu;
    float r = rsqrtf(var + 1e-5f);
    int d0 = tid * 4;
    float4 gv = *(const float4*)(gamma + d0);
    float4 bv = *(const float4*)(beta + d0);
    float4 o;
    o.x = (v.x - mu) * r * gv.x + bv.x;
    o.y = (v.y - mu) * r * gv.y + bv.y;
    o.z = (v.z - mu) * r * gv.z + bv.z;
    o.w = (v.w - mu) * r * gv.w + bv.w;
    ((float4*)(xn + (size_t)row * DD))[tid] = o;
}

// ---------------- f32 tiled GEMM: C[M,N] = A[M,K] @ B[K,N] ----------------
// EPI 0: plain store to C0 (ld = Nn)
// EPI 1: split store: cols [0,DD) -> C0, cols [DD,2DD) -> C1 (both ld = DD)
// EPI 2: C0 = acc + res (residual), ld = Nn
template<int EPI>
__global__ __launch_bounds__(256)
void gemm_tiled(const float* __restrict__ Ag, const float* __restrict__ Bg,
                float* __restrict__ C0, float* __restrict__ C1,
                const float* __restrict__ res, int Mm, int Nn, int Kk) {
    __shared__ float As[16][64];
    __shared__ float Bs[16][64];
    int tid = threadIdx.x;
    int tx = tid & 15, ty = tid >> 4;
    int rb = blockIdx.y * 64, cb = blockIdx.x * 64;

    // A-load: lane loads row ar, 4 consecutive k at ak (coalesced 64B groups)
    int ar = tid >> 2, ak = (tid & 3) * 4;
    // B-load: row bk, 4 consecutive cols at bc (fully coalesced)
    int bk = tid >> 4, bc = (tid & 15) * 4;
    const float* Aptr = Ag + (size_t)(rb + ar) * Kk + ak;
    const float* Bptr = Bg + (size_t)bk * Nn + cb + bc;

    float acc[4][4] = {};
    for (int k0 = 0; k0 < Kk; k0 += 16) {
        float4 av = *(const float4*)(Aptr + k0);
        float4 bv = *(const float4*)(Bptr + (size_t)k0 * Nn);
        __syncthreads();
        As[ak + 0][ar] = av.x;
        As[ak + 1][ar] = av.y;
        As[ak + 2][ar] = av.z;
        As[ak + 3][ar] = av.w;
        *(float4*)&Bs[bk][bc] = bv;
        __syncthreads();
        #pragma unroll
        for (int kk = 0; kk < 16; kk++) {
            float4 a = *(const float4*)&As[kk][ty << 2];
            float4 b = *(const float4*)&Bs[kk][tx << 2];
            float aa[4] = {a.x, a.y, a.z, a.w};
            float bb[4] = {b.x, b.y, b.z, b.w};
            #pragma unroll
            for (int i = 0; i < 4; i++)
                #pragma unroll
                for (int j = 0; j < 4; j++)
                    acc[i][j] = fmaf(aa[i], bb[j], acc[i][j]);
        }
    }

    int gm0 = rb + (ty << 2), gn0 = cb + (tx << 2);
    #pragma unroll
    for (int i = 0; i < 4; i++) {
        float4 o = make_float4(acc[i][0], acc[i][1], acc[i][2], acc[i][3]);
        if (EPI == 0) {
            *(float4*)&C0[(size_t)(gm0 + i) * Nn + gn0] = o;
        } else if (EPI == 1) {
            if (cb < DD) *(float4*)&C0[(size_t)(gm0 + i) * DD + gn0] = o;
            else         *(float4*)&C1[(size_t)(gm0 + i) * DD + (gn0 - DD)] = o;
        } else {
            size_t off = (size_t)(gm0 + i) * Nn + gn0;
            float4 r4 = *(const float4*)&res[off];
            o.x += r4.x; o.y += r4.y; o.z += r4.z; o.w += r4.w;
            *(float4*)&C0[off] = o;
        }
    }
}

// ---------------- small GEMM (thread-per-output; n fastest) ----------------
// EPI 0: plain. EPI 1: softplus(acc + bias[n])
template<int EPI>
__global__ __launch_bounds__(256)
void gemm_small(const float* __restrict__ Ag, const float* __restrict__ Bg,
                const float* __restrict__ bias, float* __restrict__ C,
                int Nn, int Kk) {
    int idx = blockIdx.x * 256 + threadIdx.x;
    int m = idx / Nn, n = idx - m * Nn;
    const float* ar = Ag + (size_t)m * Kk;
    float acc = 0.0f;
    #pragma unroll 4
    for (int k = 0; k < Kk; k++)
        acc = fmaf(ar[k], Bg[(size_t)k * Nn + n], acc);
    if (EPI == 1) {
        acc += bias[n];
        acc = fmaxf(acc, 0.0f) + log1pf(expf(-fabsf(acc)));  // stable softplus
    }
    C[idx] = acc;
}

// ---------------- depthwise conv1d (K=3, SAME) + SiLU ----------------
__global__ __launch_bounds__(256)
void conv_silu(const float* __restrict__ xb, const float* __restrict__ cw,
               const float* __restrict__ cb, float* __restrict__ xact) {
    int idx = blockIdx.x * 256 + threadIdx.x;   // ((b*L + l)*D + d)
    int d = idx & (DD - 1);
    int bl = idx >> 10;                          // b*L + l
    int l = bl & (LL - 1);
    float acc = cb[d];
    if (l > 0)      acc = fmaf(xb[idx - DD], cw[0 * DD + d], acc);
    acc = fmaf(xb[idx], cw[1 * DD + d], acc);
    if (l < LL - 1) acc = fmaf(xb[idx + DD], cw[2 * DD + d], acc);
    xact[idx] = acc / (1.0f + expf(-acc));       // SiLU
}

// ---------------- selective scan, chunked ----------------
// phase1: per (b, chunk, d): local scan with h_in=0 -> P = prod(a), Hc = local final h
__global__ __launch_bounds__(256)
void scan_p1(const float* __restrict__ delta, const float* __restrict__ Bm,
             const float* __restrict__ xact, const float* __restrict__ A,
             float* __restrict__ P, float* __restrict__ Hc) {
    int d = blockIdx.x * 256 + threadIdx.x;
    int c = blockIdx.y, b = blockIdx.z;
    float a_d = A[d];
    size_t base = ((size_t)(b * LL + c * LC)) * DD + d;
    float h = 0.0f, p = 1.0f;
    for (int i = 0; i < LC; i++) {
        size_t o = base + (size_t)i * DD;
        float dl = delta[o];
        float a = expf(dl * a_d);
        float bx = dl * Bm[o] * xact[o];
        h = fmaf(a, h, bx);
        p *= a;
    }
    int pc = (b * NC + c) * DD + d;
    P[pc] = p;
    Hc[pc] = h;
}

// phase2: serial carry propagation over chunks
__global__ __launch_bounds__(256)
void scan_p2(const float* __restrict__ P, const float* __restrict__ Hc,
             float* __restrict__ hin) {
    int d = blockIdx.x * 256 + threadIdx.x;
    int b = blockIdx.y;
    float carry = 0.0f;
    for (int c = 0; c < NC; c++) {
        int o = (b * NC + c) * DD + d;
        hin[o] = carry;
        carry = fmaf(P[o], carry, Hc[o]);
    }
}

// phase3: recompute local scan with correct carry, produce gated output g
__global__ __launch_bounds__(256)
void scan_p3(const float* __restrict__ delta, const float* __restrict__ Bm,
             const float* __restrict__ Cm, const float* __restrict__ xact,
             const float* __restrict__ zb, const float* __restrict__ hin,
             const float* __restrict__ A, const float* __restrict__ Dsk,
             float* __restrict__ g) {
    int d = blockIdx.x * 256 + threadIdx.x;
    int c = blockIdx.y, b = blockIdx.z;
    float a_d = A[d];
    float dskip = Dsk[d];
    float h = hin[(b * NC + c) * DD + d];
    size_t base = ((size_t)(b * LL + c * LC)) * DD + d;
    for (int i = 0; i < LC; i++) {
        size_t o = base + (size_t)i * DD;
        float dl = delta[o];
        float xa = xact[o];
        float a = expf(dl * a_d);
        h = fmaf(a, h, dl * Bm[o] * xa);
        float y = Cm[o] * h;
        float os = fmaf(xa, dskip, y);
        float zv = zb[o];
        g[o] = os * (zv / (1.0f + expf(-zv)));
    }
}

extern "C" void kernel_launch(void* const* d_in, const int* in_sizes, int n_in,
                              void* d_out, int out_size, void* d_ws, size_t ws_size,
                              hipStream_t stream) {
    const float* x      = (const float*)d_in[0];
    const float* gamma  = (const float*)d_in[1];
    const float* beta   = (const float*)d_in[2];
    const float* W_in   = (const float*)d_in[3];
    const float* conv_w = (const float*)d_in[4];
    const float* conv_b = (const float*)d_in[5];
    const float* W_xp   = (const float*)d_in[6];
    const float* W_Bg   = (const float*)d_in[7];
    const float* W_Cg   = (const float*)d_in[8];
    const float* W_dt   = (const float*)d_in[9];
    const float* b_dt   = (const float*)d_in[10];
    const float* W_Bp   = (const float*)d_in[11];
    const float* W_Cp   = (const float*)d_in[12];
    const float* A      = (const float*)d_in[13];
    const float* Dsk    = (const float*)d_in[14];
    const float* W_out  = (const float*)d_in[15];
    float* out = (float*)d_out;

    const size_t BIG = (size_t)MM * DD;           // 8,388,608
    float* w    = (float*)d_ws;
    float* xb   = w;                              // later reused as delta
    float* z    = xb + BIG;
    float* xact = z + BIG;
    float* Bmb  = xact + BIG;
    float* Cmb  = Bmb + BIG;
    float* xn   = Cmb + BIG;                      // later reused as g
    float* t1   = xn + BIG;                       // M x RK
    float* t2   = t1 + (size_t)MM * RK;           // M x DS
    float* t3   = t2 + (size_t)MM * DS;
    float* P    = t3 + (size_t)MM * DS;           // B*NC*D
    float* Hc   = P + (size_t)BB * NC * DD;
    float* hin  = Hc + (size_t)BB * NC * DD;
    float* delta = xb;                            // xb dead after conv
    float* g     = xn;                            // xn dead after in_proj

    // 1. LayerNorm
    ln_kernel<<<MM, 256, 0, stream>>>(x, gamma, beta, xn);
    // 2. in_proj (split into xb | z)
    gemm_tiled<1><<<dim3(2 * DD / 64, MM / 64), 256, 0, stream>>>(
        xn, W_in, xb, z, nullptr, MM, 2 * DD, DD);
    // 3. depthwise conv + SiLU
    conv_silu<<<(MM * DD) / 256, 256, 0, stream>>>(xb, conv_w, conv_b, xact);
    // 4. low-rank projections
    gemm_small<0><<<(MM * RK) / 256, 256, 0, stream>>>(xact, W_xp, nullptr, t1, RK, DD);
    gemm_small<0><<<(MM * DS) / 256, 256, 0, stream>>>(xact, W_Bg, nullptr, t2, DS, DD);
    gemm_small<0><<<(MM * DS) / 256, 256, 0, stream>>>(xact, W_Cg, nullptr, t3, DS, DD);
    gemm_small<1><<<(MM * DD) / 256, 256, 0, stream>>>(t1, W_dt, b_dt, delta, DD, RK);
    gemm_small<0><<<(MM * DD) / 256, 256, 0, stream>>>(t2, W_Bp, nullptr, Bmb, DD, DS);
    gemm_small<0><<<(MM * DD) / 256, 256, 0, stream>>>(t3, W_Cp, nullptr, Cmb, DD, DS);
    // 5. chunked selective scan + gating
    scan_p1<<<dim3(DD / 256, NC, BB), 256, 0, stream>>>(delta, Bmb, xact, A, P, Hc);
    scan_p2<<<dim3(DD / 256, BB), 256, 0, stream>>>(P, Hc, hin);
    scan_p3<<<dim3(DD / 256, NC, BB), 256, 0, stream>>>(delta, Bmb, Cmb, xact, z, hin,
                                                        A, Dsk, g);
    // 6. out_proj + residual
    gemm_tiled<2><<<dim3(DD / 64, MM / 64), 256, 0, stream>>>(
        g, W_out, out, nullptr, x, MM, DD, DD);
}

// Round 2
// 647.542 us; speedup vs baseline: 1.9819x; 1.9819x over previous
//
#include <hip/hip_runtime.h>
#include <math.h>

#define BB 2
#define LL 4096
#define DD 1024
#define DS 16
#define RK 64
#define MM (BB*LL)        // 8192
#define NC 64             // scan chunks
#define LC (LL/NC)        // 64

typedef __attribute__((ext_vector_type(8))) short short8;
typedef __attribute__((ext_vector_type(4))) float f32x4;

__device__ __forceinline__ unsigned short f2bf(float f) {
    union { float f; unsigned u; } v; v.f = f;
    unsigned r = v.u + 0x7fff + ((v.u >> 16) & 1);
    return (unsigned short)(r >> 16);
}

__device__ __forceinline__ void gload16(const void* g, void* l) {
    __builtin_amdgcn_global_load_lds(
        (const __attribute__((address_space(1))) unsigned int*)g,
        (__attribute__((address_space(3))) unsigned int*)l, 16, 0, 0);
}

// ---------------- LayerNorm -> bf16 output ----------------
__global__ __launch_bounds__(256)
void ln_kernel(const float* __restrict__ x, const float* __restrict__ gamma,
               const float* __restrict__ beta, unsigned short* __restrict__ xn_bf) {
    int row = blockIdx.x;
    int tid = threadIdx.x;
    const float4* xr = (const float4*)(x + (size_t)row * DD);
    float4 v = xr[tid];
    float s = v.x + v.y + v.z + v.w;
    float q = v.x*v.x + v.y*v.y + v.z*v.z + v.w*v.w;
    #pragma unroll
    for (int off = 32; off > 0; off >>= 1) {
        s += __shfl_down(s, off);
        q += __shfl_down(q, off);
    }
    __shared__ float ss[4], qq[4];
    int wv = tid >> 6;
    if ((tid & 63) == 0) { ss[wv] = s; qq[wv] = q; }
    __syncthreads();
    float S = ss[0] + ss[1] + ss[2] + ss[3];
    float Q = qq[0] + qq[1] + qq[2] + qq[3];
    float mu  = S * (1.0f / DD);
    float var = Q * (1.0f / DD) - mu * mu;
    float r = rsqrtf(var + 1e-5f);
    int d0 = tid * 4;
    float4 gv = *(const float4*)(gamma + d0);
    float4 bv = *(const float4*)(beta + d0);
    ushort4 o;
    o.x = f2bf((v.x - mu) * r * gv.x + bv.x);
    o.y = f2bf((v.y - mu) * r * gv.y + bv.y);
    o.z = f2bf((v.z - mu) * r * gv.z + bv.z);
    o.w = f2bf((v.w - mu) * r * gv.w + bv.w);
    *(ushort4*)&xn_bf[(size_t)row * DD + d0] = o;
}

// ---------------- f32 [K][N] -> bf16 [N][K] transpose-convert ----------------
__global__ __launch_bounds__(256)
void transpose_bf16(const float* __restrict__ W, unsigned short* __restrict__ WT,
                    int K, int N) {
    __shared__ float t[32][33];
    int n0 = blockIdx.x * 32, k0 = blockIdx.y * 32;
    int tx = threadIdx.x & 31, ty = threadIdx.x >> 5;   // 32 x 8
    #pragma unroll
    for (int r = 0; r < 32; r += 8)
        t[ty + r][tx] = W[(size_t)(k0 + ty + r) * N + n0 + tx];
    __syncthreads();
    #pragma unroll
    for (int r = 0; r < 32; r += 8) {
        int nl = ty + r;
        WT[(size_t)(n0 + nl) * K + k0 + tx] = f2bf(t[tx][nl]);
    }
}

// ---------------- bf16 MFMA GEMM: C[M,N] = A[M,K] @ BT[N,K]^T ----------------
// 128x128 tile, BK=32, 4 waves (2x2 of 64x64), 16x16x32 MFMA, global_load_lds,
// XOR-swizzled LDS (seg ^= (row>>1)&3, both-sides: pre-swizzled global source).
// EPI 1: split store cols [0,DD)->C0, [DD,2DD)->C1 (ld=DD)
// EPI 2: C0 = acc + res (ld=N)
template<int EPI>
__global__ __launch_bounds__(256)
void gemm_mfma(const unsigned short* __restrict__ A, const unsigned short* __restrict__ BT,
               float* __restrict__ C0, float* __restrict__ C1,
               const float* __restrict__ res, int M, int N, int K) {
    __shared__ unsigned short As[128 * 32];
    __shared__ unsigned short Bs[128 * 32];
    int tid = threadIdx.x;
    int rb = blockIdx.y * 128, cb = blockIdx.x * 128;
    int wave = tid >> 6, lane = tid & 63;
    int wr = wave >> 1, wc = wave & 1;
    int fr = lane & 15, fs = lane >> 4;      // fragment row / k-segment

    // staging: load i covers LDS slot (row = i>>2, seg = i&3), i = tid (+256)
    int r0 = tid >> 2, s0 = tid & 3;
    int sw0 = s0 ^ ((r0 >> 1) & 3);          // pre-swizzled global segment
    const unsigned short* gA = A + (size_t)(rb + r0) * K + sw0 * 8;
    const unsigned short* gB = BT + (size_t)(cb + r0) * K + sw0 * 8;
    size_t half = (size_t)64 * K;            // rows 64..127 (same swizzle: (r0+64)>>1 &3 == (r0>>1)&3)
    char* lA0 = (char*)As + tid * 16;
    char* lA1 = (char*)As + (tid + 256) * 16;
    char* lB0 = (char*)Bs + tid * 16;
    char* lB1 = (char*)Bs + (tid + 256) * 16;

    f32x4 acc[4][4] = {};

    #pragma unroll 1
    for (int k0 = 0; k0 < K; k0 += 32) {
        __syncthreads();
        gload16(gA + k0, lA0);
        gload16(gA + half + k0, lA1);
        gload16(gB + k0, lB0);
        gload16(gB + half + k0, lB1);
        __syncthreads();

        short8 af[4], bf[4];
        #pragma unroll
        for (int i = 0; i < 4; i++) {
            int row = (wr << 6) + (i << 4) + fr;
            int off = (row << 5) + ((fs ^ ((row >> 1) & 3)) << 3);  // ushort units
            af[i] = *(const short8*)&As[off];
        }
        #pragma unroll
        for (int j = 0; j < 4; j++) {
            int row = (wc << 6) + (j << 4) + fr;
            int off = (row << 5) + ((fs ^ ((row >> 1) & 3)) << 3);
            bf[j] = *(const short8*)&Bs[off];
        }
        #pragma unroll
        for (int i = 0; i < 4; i++)
            #pragma unroll
            for (int j = 0; j < 4; j++)
                acc[i][j] = __builtin_amdgcn_mfma_f32_16x16x32_bf16(af[i], bf[j], acc[i][j], 0, 0, 0);
    }

    // epilogue: C/D layout col = lane&15, row = (lane>>4)*4 + reg
    int row0 = rb + (wr << 6) + (fs << 2);
    int col0 = (wc << 6) + fr;
    if (EPI == 1) {
        float* Cd = (cb < DD) ? C0 : C1;
        int cbase = (cb < DD) ? cb : cb - DD;
        #pragma unroll
        for (int i = 0; i < 4; i++)
            #pragma unroll
            for (int j = 0; j < 4; j++) {
                int col = cbase + col0 + (j << 4);
                #pragma unroll
                for (int q = 0; q < 4; q++)
                    Cd[(size_t)(row0 + (i << 4) + q) * DD + col] = acc[i][j][q];
            }
    } else {
        #pragma unroll
        for (int i = 0; i < 4; i++)
            #pragma unroll
            for (int j = 0; j < 4; j++) {
                int col = cb + col0 + (j << 4);
                #pragma unroll
                for (int q = 0; q < 4; q++) {
                    size_t off = (size_t)(row0 + (i << 4) + q) * N + col;
                    C0[off] = acc[i][j][q] + res[off];
                }
            }
    }
}

// ---------------- small GEMM (thread-per-output; n fastest) ----------------
template<int EPI>
__global__ __launch_bounds__(256)
void gemm_small(const float* __restrict__ Ag, const float* __restrict__ Bg,
                const float* __restrict__ bias, float* __restrict__ C,
                int Nn, int Kk) {
    int idx = blockIdx.x * 256 + threadIdx.x;
    int m = idx / Nn, n = idx - m * Nn;
    const float* ar = Ag + (size_t)m * Kk;
    float acc = 0.0f;
    #pragma unroll 4
    for (int k = 0; k < Kk; k++)
        acc = fmaf(ar[k], Bg[(size_t)k * Nn + n], acc);
    if (EPI == 1) {
        acc += bias[n];
        acc = fmaxf(acc, 0.0f) + log1pf(expf(-fabsf(acc)));
    }
    C[idx] = acc;
}

// ---------------- depthwise conv1d (K=3, SAME) + SiLU ----------------
__global__ __launch_bounds__(256)
void conv_silu(const float* __restrict__ xb, const float* __restrict__ cw,
               const float* __restrict__ cb, float* __restrict__ xact) {
    int idx = blockIdx.x * 256 + threadIdx.x;
    int d = idx & (DD - 1);
    int bl = idx >> 10;
    int l = bl & (LL - 1);
    float acc = cb[d];
    if (l > 0)      acc = fmaf(xb[idx - DD], cw[0 * DD + d], acc);
    acc = fmaf(xb[idx], cw[1 * DD + d], acc);
    if (l < LL - 1) acc = fmaf(xb[idx + DD], cw[2 * DD + d], acc);
    xact[idx] = acc / (1.0f + expf(-acc));
}

// ---------------- selective scan, chunked ----------------
__global__ __launch_bounds__(256)
void scan_p1(const float* __restrict__ delta, const float* __restrict__ Bm,
             const float* __restrict__ xact, const float* __restrict__ A,
             float* __restrict__ P, float* __restrict__ Hc) {
    int d = blockIdx.x * 256 + threadIdx.x;
    int c = blockIdx.y, b = blockIdx.z;
    float a_d = A[d];
    size_t base = ((size_t)(b * LL + c * LC)) * DD + d;
    float h = 0.0f, p = 1.0f;
    for (int i = 0; i < LC; i++) {
        size_t o = base + (size_t)i * DD;
        float dl = delta[o];
        float a = expf(dl * a_d);
        float bx = dl * Bm[o] * xact[o];
        h = fmaf(a, h, bx);
        p *= a;
    }
    int pc = (b * NC + c) * DD + d;
    P[pc] = p;
    Hc[pc] = h;
}

__global__ __launch_bounds__(256)
void scan_p2(const float* __restrict__ P, const float* __restrict__ Hc,
             float* __restrict__ hin) {
    int d = blockIdx.x * 256 + threadIdx.x;
    int b = blockIdx.y;
    float carry = 0.0f;
    for (int c = 0; c < NC; c++) {
        int o = (b * NC + c) * DD + d;
        hin[o] = carry;
        carry = fmaf(P[o], carry, Hc[o]);
    }
}

__global__ __launch_bounds__(256)
void scan_p3(const float* __restrict__ delta, const float* __restrict__ Bm,
             const float* __restrict__ Cm, const float* __restrict__ xact,
             const float* __restrict__ zb, const float* __restrict__ hin,
             const float* __restrict__ A, const float* __restrict__ Dsk,
             unsigned short* __restrict__ g) {
    int d = blockIdx.x * 256 + threadIdx.x;
    int c = blockIdx.y, b = blockIdx.z;
    float a_d = A[d];
    float dskip = Dsk[d];
    float h = hin[(b * NC + c) * DD + d];
    size_t base = ((size_t)(b * LL + c * LC)) * DD + d;
    for (int i = 0; i < LC; i++) {
        size_t o = base + (size_t)i * DD;
        float dl = delta[o];
        float xa = xact[o];
        float a = expf(dl * a_d);
        h = fmaf(a, h, dl * Bm[o] * xa);
        float y = Cm[o] * h;
        float os = fmaf(xa, dskip, y);
        float zv = zb[o];
        g[o] = f2bf(os * (zv / (1.0f + expf(-zv))));
    }
}

extern "C" void kernel_launch(void* const* d_in, const int* in_sizes, int n_in,
                              void* d_out, int out_size, void* d_ws, size_t ws_size,
                              hipStream_t stream) {
    const float* x      = (const float*)d_in[0];
    const float* gamma  = (const float*)d_in[1];
    const float* beta   = (const float*)d_in[2];
    const float* W_in   = (const float*)d_in[3];
    const float* conv_w = (const float*)d_in[4];
    const float* conv_b = (const float*)d_in[5];
    const float* W_xp   = (const float*)d_in[6];
    const float* W_Bg   = (const float*)d_in[7];
    const float* W_Cg   = (const float*)d_in[8];
    const float* W_dt   = (const float*)d_in[9];
    const float* b_dt   = (const float*)d_in[10];
    const float* W_Bp   = (const float*)d_in[11];
    const float* W_Cp   = (const float*)d_in[12];
    const float* A      = (const float*)d_in[13];
    const float* Dsk    = (const float*)d_in[14];
    const float* W_out  = (const float*)d_in[15];
    float* out = (float*)d_out;

    const size_t BIG = (size_t)MM * DD;
    float* w    = (float*)d_ws;
    float* xb   = w;                              // reused as delta
    float* z    = xb + BIG;
    float* xact = z + BIG;
    float* Bmb  = xact + BIG;
    float* Cmb  = Bmb + BIG;
    float* t1   = Cmb + BIG;                      // M x RK
    float* t2   = t1 + (size_t)MM * RK;
    float* t3   = t2 + (size_t)MM * DS;
    float* P    = t3 + (size_t)MM * DS;
    float* Hc   = P + (size_t)BB * NC * DD;
    float* hin  = Hc + (size_t)BB * NC * DD;
    unsigned short* xn_bf = (unsigned short*)(hin + (size_t)BB * NC * DD);  // M x D
    unsigned short* WinT  = xn_bf + BIG;          // 2D x D
    unsigned short* WoutT = WinT + (size_t)2 * DD * DD;  // D x D
    float* delta = xb;
    unsigned short* g_bf = xn_bf;                 // xn dead after in_proj

    // 0. weight transpose+convert  [K][N] f32 -> [N][K] bf16
    transpose_bf16<<<dim3(2 * DD / 32, DD / 32), 256, 0, stream>>>(W_in, WinT, DD, 2 * DD);
    transpose_bf16<<<dim3(DD / 32, DD / 32), 256, 0, stream>>>(W_out, WoutT, DD, DD);
    // 1. LayerNorm (bf16 out)
    ln_kernel<<<MM, 256, 0, stream>>>(x, gamma, beta, xn_bf);
    // 2. in_proj (MFMA, split into xb | z)
    gemm_mfma<1><<<dim3(2 * DD / 128, MM / 128), 256, 0, stream>>>(
        xn_bf, WinT, xb, z, nullptr, MM, 2 * DD, DD);
    // 3. depthwise conv + SiLU
    conv_silu<<<(MM * DD) / 256, 256, 0, stream>>>(xb, conv_w, conv_b, xact);
    // 4. low-rank projections
    gemm_small<0><<<(MM * RK) / 256, 256, 0, stream>>>(xact, W_xp, nullptr, t1, RK, DD);
    gemm_small<0><<<(MM * DS) / 256, 256, 0, stream>>>(xact, W_Bg, nullptr, t2, DS, DD);
    gemm_small<0><<<(MM * DS) / 256, 256, 0, stream>>>(xact, W_Cg, nullptr, t3, DS, DD);
    gemm_small<1><<<(MM * DD) / 256, 256, 0, stream>>>(t1, W_dt, b_dt, delta, DD, RK);
    gemm_small<0><<<(MM * DD) / 256, 256, 0, stream>>>(t2, W_Bp, nullptr, Bmb, DD, DS);
    gemm_small<0><<<(MM * DD) / 256, 256, 0, stream>>>(t3, W_Cp, nullptr, Cmb, DD, DS);
    // 5. chunked selective scan + gating (bf16 g out)
    scan_p1<<<dim3(DD / 256, NC, BB), 256, 0, stream>>>(delta, Bmb, xact, A, P, Hc);
    scan_p2<<<dim3(DD / 256, BB), 256, 0, stream>>>(P, Hc, hin);
    scan_p3<<<dim3(DD / 256, NC, BB), 256, 0, stream>>>(delta, Bmb, Cmb, xact, z, hin,
                                                        A, Dsk, g_bf);
    // 6. out_proj + residual (MFMA)
    gemm_mfma<2><<<dim3(DD / 128, MM / 128), 256, 0, stream>>>(
        g_bf, WoutT, out, nullptr, x, MM, DD, DD);
}

// Round 3
// 263.733 us; speedup vs baseline: 4.8662x; 2.4553x over previous
//
#include <hip/hip_runtime.h>
#include <math.h>

#define BB 2
#define LL 4096
#define DD 1024
#define DS 16
#define RK 64
#define MM (BB*LL)        // 8192
#define NC 64             // scan chunks
#define LC (LL/NC)        // 64

typedef __attribute__((ext_vector_type(8))) short short8;
typedef __attribute__((ext_vector_type(4))) float f32x4;

__device__ __forceinline__ unsigned short f2bf(float f) {
    union { float f; unsigned u; } v; v.f = f;
    unsigned r = v.u + 0x7fff + ((v.u >> 16) & 1);
    return (unsigned short)(r >> 16);
}
__device__ __forceinline__ float bf2f(unsigned short u) {
    union { unsigned u; float f; } v; v.u = ((unsigned)u) << 16;
    return v.f;
}
__device__ __forceinline__ float softplusf(float v) {
    return fmaxf(v, 0.0f) + log1pf(expf(-fabsf(v)));
}
__device__ __forceinline__ void gload16(const void* g, void* l) {
    __builtin_amdgcn_global_load_lds(
        (const __attribute__((address_space(1))) unsigned int*)g,
        (__attribute__((address_space(3))) unsigned int*)l, 16, 0, 0);
}

// ---------------- LayerNorm -> bf16 ----------------
__global__ __launch_bounds__(256)
void ln_kernel(const float* __restrict__ x, const float* __restrict__ gamma,
               const float* __restrict__ beta, unsigned short* __restrict__ xn_bf) {
    int row = blockIdx.x;
    int tid = threadIdx.x;
    const float4* xr = (const float4*)(x + (size_t)row * DD);
    float4 v = xr[tid];
    float s = v.x + v.y + v.z + v.w;
    float q = v.x*v.x + v.y*v.y + v.z*v.z + v.w*v.w;
    #pragma unroll
    for (int off = 32; off > 0; off >>= 1) {
        s += __shfl_down(s, off);
        q += __shfl_down(q, off);
    }
    __shared__ float ss[4], qq[4];
    int wv = tid >> 6;
    if ((tid & 63) == 0) { ss[wv] = s; qq[wv] = q; }
    __syncthreads();
    float S = ss[0] + ss[1] + ss[2] + ss[3];
    float Q = qq[0] + qq[1] + qq[2] + qq[3];
    float mu  = S * (1.0f / DD);
    float var = Q * (1.0f / DD) - mu * mu;
    float r = rsqrtf(var + 1e-5f);
    int d0 = tid * 4;
    float4 gv = *(const float4*)(gamma + d0);
    float4 bv = *(const float4*)(beta + d0);
    ushort4 o;
    o.x = f2bf((v.x - mu) * r * gv.x + bv.x);
    o.y = f2bf((v.y - mu) * r * gv.y + bv.y);
    o.z = f2bf((v.z - mu) * r * gv.z + bv.z);
    o.w = f2bf((v.w - mu) * r * gv.w + bv.w);
    *(ushort4*)&xn_bf[(size_t)row * DD + d0] = o;
}

// ---------------- f32 [K][N] -> bf16 [N][K] transpose-convert ----------------
__global__ __launch_bounds__(256)
void transpose_bf16(const float* __restrict__ W, unsigned short* __restrict__ WT,
                    int K, int N) {
    __shared__ float t[32][33];
    int n0 = blockIdx.x * 32, k0 = blockIdx.y * 32;
    int tx = threadIdx.x & 31, ty = threadIdx.x >> 5;   // 32 x 8
    #pragma unroll
    for (int r = 0; r < 32; r += 8)
        t[ty + r][tx] = W[(size_t)(k0 + ty + r) * N + n0 + tx];
    __syncthreads();
    #pragma unroll
    for (int r = 0; r < 32; r += 8) {
        int nl = ty + r;
        WT[(size_t)(n0 + nl) * K + k0 + tx] = f2bf(t[tx][nl]);
    }
}

// ---- pack WgT[128][1024]: n<64 W_xp, 64..79 W_Bg, 80..95 W_Cg, else 0 ----
__global__ __launch_bounds__(256)
void build_wg(const float* __restrict__ W_xp, const float* __restrict__ W_Bg,
              const float* __restrict__ W_Cg, unsigned short* __restrict__ WgT) {
    int idx = blockIdx.x * 256 + threadIdx.x;   // [n][k], k fastest
    int k = idx & 1023, n = idx >> 10;
    float v = 0.0f;
    if (n < 64)       v = W_xp[k * RK + n];
    else if (n < 80)  v = W_Bg[k * DS + (n - 64)];
    else if (n < 96)  v = W_Cg[k * DS + (n - 80)];
    WgT[idx] = f2bf(v);
}

// ---- pack WupT[3072][128]: block-diag(W_dt[64,1024], W_Bp[16,1024], W_Cp[16,1024]) ----
__global__ __launch_bounds__(256)
void build_wup(const float* __restrict__ W_dt, const float* __restrict__ W_Bp,
               const float* __restrict__ W_Cp, unsigned short* __restrict__ WupT) {
    int idx = blockIdx.x * 256 + threadIdx.x;   // [n][k], k fastest
    int k = idx & 127, n = idx >> 7;
    float v = 0.0f;
    if (n < 1024)      { if (k < 64)            v = W_dt[k * 1024 + n]; }
    else if (n < 2048) { if (k >= 64 && k < 80) v = W_Bp[(k - 64) * 1024 + (n - 1024)]; }
    else               { if (k >= 80 && k < 96) v = W_Cp[(k - 80) * 1024 + (n - 2048)]; }
    WupT[idx] = f2bf(v);
}

// ---------------- bf16 MFMA GEMM: C[M,N] = A[M,K] @ BT[N,K]^T ----------------
// 128x128 tile, BK=32, 4 waves, 16x16x32 MFMA, global_load_lds, XOR swizzle.
// EPI 0: bf16 store, ld=N
// EPI 1: split bf16 store: cols [0,DD)->C0, [DD,2DD)->C1 (ld=DD)
// EPI 2: f32 store = acc + res (ld=N)
// EPI 3: f32 partial store (split-K over blockIdx.z, 4 slices) to C0 + z*M*N
template<int EPI>
__global__ __launch_bounds__(256)
void gemm_mfma(const unsigned short* __restrict__ A, const unsigned short* __restrict__ BT,
               void* __restrict__ C0v, void* __restrict__ C1v,
               const float* __restrict__ res, int M, int N, int K) {
    __shared__ unsigned short As[128 * 32];
    __shared__ unsigned short Bs[128 * 32];
    int tid = threadIdx.x;
    int rb = blockIdx.y * 128, cb = blockIdx.x * 128;
    int wave = tid >> 6, lane = tid & 63;
    int wr = wave >> 1, wc = wave & 1;
    int fr = lane & 15, fs = lane >> 4;

    int r0 = tid >> 2, s0 = tid & 3;
    int sw0 = s0 ^ ((r0 >> 1) & 3);
    const unsigned short* gA = A + (size_t)(rb + r0) * K + sw0 * 8;
    const unsigned short* gB = BT + (size_t)(cb + r0) * K + sw0 * 8;
    size_t half = (size_t)64 * K;
    char* lA0 = (char*)As + tid * 16;
    char* lA1 = (char*)As + (tid + 256) * 16;
    char* lB0 = (char*)Bs + tid * 16;
    char* lB1 = (char*)Bs + (tid + 256) * 16;

    int kb = 0, ke = K;
    if (EPI == 3) { kb = blockIdx.z * (K >> 2); ke = kb + (K >> 2); }

    f32x4 acc[4][4] = {};

    #pragma unroll 1
    for (int k0 = kb; k0 < ke; k0 += 32) {
        __syncthreads();
        gload16(gA + k0, lA0);
        gload16(gA + half + k0, lA1);
        gload16(gB + k0, lB0);
        gload16(gB + half + k0, lB1);
        __syncthreads();

        short8 af[4], bfr[4];
        #pragma unroll
        for (int i = 0; i < 4; i++) {
            int row = (wr << 6) + (i << 4) + fr;
            int off = (row << 5) + ((fs ^ ((row >> 1) & 3)) << 3);
            af[i] = *(const short8*)&As[off];
        }
        #pragma unroll
        for (int j = 0; j < 4; j++) {
            int row = (wc << 6) + (j << 4) + fr;
            int off = (row << 5) + ((fs ^ ((row >> 1) & 3)) << 3);
            bfr[j] = *(const short8*)&Bs[off];
        }
        #pragma unroll
        for (int i = 0; i < 4; i++)
            #pragma unroll
            for (int j = 0; j < 4; j++)
                acc[i][j] = __builtin_amdgcn_mfma_f32_16x16x32_bf16(af[i], bfr[j], acc[i][j], 0, 0, 0);
    }

    // C/D layout: col = lane&15, row = (lane>>4)*4 + reg
    int row0 = rb + (wr << 6) + (fs << 2);
    int col0 = (wc << 6) + fr;
    if (EPI == 0) {
        unsigned short* C0 = (unsigned short*)C0v;
        #pragma unroll
        for (int i = 0; i < 4; i++)
            #pragma unroll
            for (int j = 0; j < 4; j++) {
                int col = cb + col0 + (j << 4);
                #pragma unroll
                for (int q = 0; q < 4; q++)
                    C0[(size_t)(row0 + (i << 4) + q) * N + col] = f2bf(acc[i][j][q]);
            }
    } else if (EPI == 1) {
        unsigned short* Cd = (cb < DD) ? (unsigned short*)C0v : (unsigned short*)C1v;
        int cbase = (cb < DD) ? cb : cb - DD;
        #pragma unroll
        for (int i = 0; i < 4; i++)
            #pragma unroll
            for (int j = 0; j < 4; j++) {
                int col = cbase + col0 + (j << 4);
                #pragma unroll
                for (int q = 0; q < 4; q++)
                    Cd[(size_t)(row0 + (i << 4) + q) * DD + col] = f2bf(acc[i][j][q]);
            }
    } else if (EPI == 2) {
        float* C0 = (float*)C0v;
        #pragma unroll
        for (int i = 0; i < 4; i++)
            #pragma unroll
            for (int j = 0; j < 4; j++) {
                int col = cb + col0 + (j << 4);
                #pragma unroll
                for (int q = 0; q < 4; q++) {
                    size_t off = (size_t)(row0 + (i << 4) + q) * N + col;
                    C0[off] = acc[i][j][q] + res[off];
                }
            }
    } else {
        float* C0 = (float*)C0v + (size_t)blockIdx.z * M * N;
        #pragma unroll
        for (int i = 0; i < 4; i++)
            #pragma unroll
            for (int j = 0; j < 4; j++) {
                int col = cb + col0 + (j << 4);
                #pragma unroll
                for (int q = 0; q < 4; q++)
                    C0[(size_t)(row0 + (i << 4) + q) * N + col] = acc[i][j][q];
            }
    }
}

// ---- reduce 4 split-K partials (f32) -> bf16 t ----
__global__ __launch_bounds__(256)
void reduce_t(const float* __restrict__ tp, unsigned short* __restrict__ t_bf) {
    int idx = blockIdx.x * 256 + threadIdx.x;       // over M*128/4
    const size_t Q = (size_t)MM * 128 / 4;
    float4 a = ((const float4*)tp)[idx];
    float4 b = ((const float4*)tp)[idx + Q];
    float4 c = ((const float4*)tp)[idx + 2 * Q];
    float4 d = ((const float4*)tp)[idx + 3 * Q];
    ushort4 o;
    o.x = f2bf(a.x + b.x + c.x + d.x);
    o.y = f2bf(a.y + b.y + c.y + d.y);
    o.z = f2bf(a.z + b.z + c.z + d.z);
    o.w = f2bf(a.w + b.w + c.w + d.w);
    ((ushort4*)t_bf)[idx] = o;
}

// ---------------- depthwise conv1d (K=3, SAME) + SiLU, bf16 in/out ----------------
__global__ __launch_bounds__(256)
void conv_silu(const unsigned short* __restrict__ xb, const float* __restrict__ cw,
               const float* __restrict__ cb, unsigned short* __restrict__ xact) {
    int idx8 = blockIdx.x * 256 + threadIdx.x;
    size_t e = (size_t)idx8 * 8;
    int d0 = (int)(e & (DD - 1));
    int bl = (int)(e >> 10);
    int l = bl & (LL - 1);
    short8 cur = *(const short8*)&xb[e];
    short8 prv = {}, nxt = {};
    if (l > 0)      prv = *(const short8*)&xb[e - DD];
    if (l < LL - 1) nxt = *(const short8*)&xb[e + DD];
    short8 o;
    #pragma unroll
    for (int j = 0; j < 8; j++) {
        int d = d0 + j;
        float acc = cb[d];
        acc = fmaf(bf2f((unsigned short)prv[j]), cw[0 * DD + d], acc);
        acc = fmaf(bf2f((unsigned short)cur[j]), cw[1 * DD + d], acc);
        acc = fmaf(bf2f((unsigned short)nxt[j]), cw[2 * DD + d], acc);
        float s = acc / (1.0f + expf(-acc));
        o[j] = (short)f2bf(s);
    }
    *(short8*)&xact[e] = o;
}

// ---------------- selective scan, chunked; params from dBC (bf16, ld=3072) ----------------
__global__ __launch_bounds__(256)
void scan_p1(const unsigned short* __restrict__ dbc, const unsigned short* __restrict__ xact,
             const float* __restrict__ b_dt, const float* __restrict__ A,
             float* __restrict__ P, float* __restrict__ Hc) {
    int d = blockIdx.x * 256 + threadIdx.x;
    int c = blockIdx.y, b = blockIdx.z;
    float a_d = A[d], bd = b_dt[d];
    size_t row0 = (size_t)(b * LL + c * LC);
    float h = 0.0f, p = 1.0f;
    for (int i = 0; i < LC; i++) {
        size_t r = row0 + i;
        size_t o3 = r * 3072 + d;
        float dl = softplusf(bf2f(dbc[o3]) + bd);
        float bm = bf2f(dbc[o3 + 1024]);
        float xa = bf2f(xact[r * DD + d]);
        float a = expf(dl * a_d);
        h = fmaf(a, h, dl * bm * xa);
        p *= a;
    }
    int pc = (b * NC + c) * DD + d;
    P[pc] = p;
    Hc[pc] = h;
}

__global__ __launch_bounds__(256)
void scan_p2(const float* __restrict__ P, const float* __restrict__ Hc,
             float* __restrict__ hin) {
    int d = blockIdx.x * 256 + threadIdx.x;
    int b = blockIdx.y;
    float carry = 0.0f;
    for (int c = 0; c < NC; c++) {
        int o = (b * NC + c) * DD + d;
        hin[o] = carry;
        carry = fmaf(P[o], carry, Hc[o]);
    }
}

__global__ __launch_bounds__(256)
void scan_p3(const unsigned short* __restrict__ dbc, const unsigned short* __restrict__ xact,
             const unsigned short* __restrict__ zb, const float* __restrict__ hin,
             const float* __restrict__ b_dt, const float* __restrict__ A,
             const float* __restrict__ Dsk, unsigned short* __restrict__ g) {
    int d = blockIdx.x * 256 + threadIdx.x;
    int c = blockIdx.y, b = blockIdx.z;
    float a_d = A[d], bd = b_dt[d], dskip = Dsk[d];
    float h = hin[(b * NC + c) * DD + d];
    size_t row0 = (size_t)(b * LL + c * LC);
    for (int i = 0; i < LC; i++) {
        size_t r = row0 + i;
        size_t o3 = r * 3072 + d;
        size_t o = r * DD + d;
        float dl = softplusf(bf2f(dbc[o3]) + bd);
        float bm = bf2f(dbc[o3 + 1024]);
        float cm = bf2f(dbc[o3 + 2048]);
        float xa = bf2f(xact[o]);
        float a = expf(dl * a_d);
        h = fmaf(a, h, dl * bm * xa);
        float y = cm * h;
        float os = fmaf(xa, dskip, y);
        float zv = bf2f(zb[o]);
        g[o] = f2bf(os * (zv / (1.0f + expf(-zv))));
    }
}

extern "C" void kernel_launch(void* const* d_in, const int* in_sizes, int n_in,
                              void* d_out, int out_size, void* d_ws, size_t ws_size,
                              hipStream_t stream) {
    const float* x      = (const float*)d_in[0];
    const float* gamma  = (const float*)d_in[1];
    const float* beta   = (const float*)d_in[2];
    const float* W_in   = (const float*)d_in[3];
    const float* conv_w = (const float*)d_in[4];
    const float* conv_b = (const float*)d_in[5];
    const float* W_xp   = (const float*)d_in[6];
    const float* W_Bg   = (const float*)d_in[7];
    const float* W_Cg   = (const float*)d_in[8];
    const float* W_dt   = (const float*)d_in[9];
    const float* b_dt   = (const float*)d_in[10];
    const float* W_Bp   = (const float*)d_in[11];
    const float* W_Cp   = (const float*)d_in[12];
    const float* A      = (const float*)d_in[13];
    const float* Dsk    = (const float*)d_in[14];
    const float* W_out  = (const float*)d_in[15];
    float* out = (float*)d_out;

    const size_t BIG = (size_t)MM * DD;           // 8.39M elements
    char* p = (char*)d_ws;
    unsigned short* xn_bf  = (unsigned short*)p;  p += BIG * 2;       // reused as g
    unsigned short* xb_bf  = (unsigned short*)p;  p += BIG * 2;
    unsigned short* z_bf   = (unsigned short*)p;  p += BIG * 2;
    unsigned short* xact_bf= (unsigned short*)p;  p += BIG * 2;
    unsigned short* t_bf   = (unsigned short*)p;  p += (size_t)MM * 128 * 2;
    unsigned short* dBC    = (unsigned short*)p;  p += (size_t)MM * 3072 * 2;
    float* tpart = (float*)p;                     p += (size_t)4 * MM * 128 * 4;
    float* P     = (float*)p;                     p += (size_t)BB * NC * DD * 4;
    float* Hc    = (float*)p;                     p += (size_t)BB * NC * DD * 4;
    float* hin   = (float*)p;                     p += (size_t)BB * NC * DD * 4;
    unsigned short* WinT  = (unsigned short*)p;   p += (size_t)2 * DD * DD * 2;
    unsigned short* WoutT = (unsigned short*)p;   p += (size_t)DD * DD * 2;
    unsigned short* WgT   = (unsigned short*)p;   p += (size_t)128 * DD * 2;
    unsigned short* WupT  = (unsigned short*)p;   p += (size_t)3072 * 128 * 2;
    unsigned short* g_bf  = xn_bf;

    // 0. weight prep
    transpose_bf16<<<dim3(2 * DD / 32, DD / 32), 256, 0, stream>>>(W_in, WinT, DD, 2 * DD);
    transpose_bf16<<<dim3(DD / 32, DD / 32), 256, 0, stream>>>(W_out, WoutT, DD, DD);
    build_wg<<<(128 * DD) / 256, 256, 0, stream>>>(W_xp, W_Bg, W_Cg, WgT);
    build_wup<<<(3072 * 128) / 256, 256, 0, stream>>>(W_dt, W_Bp, W_Cp, WupT);
    // 1. LayerNorm
    ln_kernel<<<MM, 256, 0, stream>>>(x, gamma, beta, xn_bf);
    // 2. in_proj -> xb | z (bf16)
    gemm_mfma<1><<<dim3(2 * DD / 128, MM / 128), 256, 0, stream>>>(
        xn_bf, WinT, xb_bf, z_bf, nullptr, MM, 2 * DD, DD);
    // 3. depthwise conv + SiLU
    conv_silu<<<(MM * DD / 8) / 256, 256, 0, stream>>>(xb_bf, conv_w, conv_b, xact_bf);
    // 4a. down-proj (split-K=4) + reduce -> t (M x 128 bf16)
    gemm_mfma<3><<<dim3(1, MM / 128, 4), 256, 0, stream>>>(
        xact_bf, WgT, tpart, nullptr, nullptr, MM, 128, DD);
    reduce_t<<<(MM * 128 / 4) / 256, 256, 0, stream>>>(tpart, t_bf);
    // 4b. up-proj -> dBC = [delta_raw | Bm | Cm] (M x 3072 bf16)
    gemm_mfma<0><<<dim3(3072 / 128, MM / 128), 256, 0, stream>>>(
        t_bf, WupT, dBC, nullptr, nullptr, MM, 3072, 128);
    // 5. chunked selective scan + gating
    scan_p1<<<dim3(DD / 256, NC, BB), 256, 0, stream>>>(dBC, xact_bf, b_dt, A, P, Hc);
    scan_p2<<<dim3(DD / 256, BB), 256, 0, stream>>>(P, Hc, hin);
    scan_p3<<<dim3(DD / 256, NC, BB), 256, 0, stream>>>(dBC, xact_bf, z_bf, hin,
                                                        b_dt, A, Dsk, g_bf);
    // 6. out_proj + residual (f32 out)
    gemm_mfma<2><<<dim3(DD / 128, MM / 128), 256, 0, stream>>>(
        g_bf, WoutT, out, nullptr, x, MM, DD, DD);
}

// Round 4
// 240.630 us; speedup vs baseline: 5.3334x; 1.0960x over previous
//
#include <hip/hip_runtime.h>
#include <math.h>

#define BB 2
#define LL 4096
#define DD 1024
#define DS 16
#define RK 64
#define MM (BB*LL)        // 8192
#define NC 64             // scan chunks
#define LC (LL/NC)        // 64

typedef __attribute__((ext_vector_type(8))) short short8;
typedef __attribute__((ext_vector_type(4))) float f32x4;

__device__ __forceinline__ unsigned short f2bf(float f) {
    union { float f; unsigned u; } v; v.f = f;
    unsigned r = v.u + 0x7fff + ((v.u >> 16) & 1);
    return (unsigned short)(r >> 16);
}
__device__ __forceinline__ float bf2f(unsigned short u) {
    union { unsigned u; float f; } v; v.u = ((unsigned)u) << 16;
    return v.f;
}
__device__ __forceinline__ float softplusf(float v) {
    return fmaxf(v, 0.0f) + log1pf(expf(-fabsf(v)));
}
__device__ __forceinline__ void gload16(const void* g, void* l) {
    __builtin_amdgcn_global_load_lds(
        (const __attribute__((address_space(1))) unsigned int*)g,
        (__attribute__((address_space(3))) unsigned int*)l, 16, 0, 0);
}

// ---------------- LayerNorm -> bf16 ----------------
__global__ __launch_bounds__(256)
void ln_kernel(const float* __restrict__ x, const float* __restrict__ gamma,
               const float* __restrict__ beta, unsigned short* __restrict__ xn_bf) {
    int row = blockIdx.x;
    int tid = threadIdx.x;
    const float4* xr = (const float4*)(x + (size_t)row * DD);
    float4 v = xr[tid];
    float s = v.x + v.y + v.z + v.w;
    float q = v.x*v.x + v.y*v.y + v.z*v.z + v.w*v.w;
    #pragma unroll
    for (int off = 32; off > 0; off >>= 1) {
        s += __shfl_down(s, off);
        q += __shfl_down(q, off);
    }
    __shared__ float ss[4], qq[4];
    int wv = tid >> 6;
    if ((tid & 63) == 0) { ss[wv] = s; qq[wv] = q; }
    __syncthreads();
    float S = ss[0] + ss[1] + ss[2] + ss[3];
    float Q = qq[0] + qq[1] + qq[2] + qq[3];
    float mu  = S * (1.0f / DD);
    float var = Q * (1.0f / DD) - mu * mu;
    float r = rsqrtf(var + 1e-5f);
    int d0 = tid * 4;
    float4 gv = *(const float4*)(gamma + d0);
    float4 bv = *(const float4*)(beta + d0);
    ushort4 o;
    o.x = f2bf((v.x - mu) * r * gv.x + bv.x);
    o.y = f2bf((v.y - mu) * r * gv.y + bv.y);
    o.z = f2bf((v.z - mu) * r * gv.z + bv.z);
    o.w = f2bf((v.w - mu) * r * gv.w + bv.w);
    *(ushort4*)&xn_bf[(size_t)row * DD + d0] = o;
}

// ---------------- f32 [K][N] -> bf16 [N][K] transpose-convert ----------------
__global__ __launch_bounds__(256)
void transpose_bf16(const float* __restrict__ W, unsigned short* __restrict__ WT,
                    int K, int N) {
    __shared__ float t[32][33];
    int n0 = blockIdx.x * 32, k0 = blockIdx.y * 32;
    int tx = threadIdx.x & 31, ty = threadIdx.x >> 5;   // 32 x 8
    #pragma unroll
    for (int r = 0; r < 32; r += 8)
        t[ty + r][tx] = W[(size_t)(k0 + ty + r) * N + n0 + tx];
    __syncthreads();
    #pragma unroll
    for (int r = 0; r < 32; r += 8) {
        int nl = ty + r;
        WT[(size_t)(n0 + nl) * K + k0 + tx] = f2bf(t[tx][nl]);
    }
}

// ---- pack WgT[128][1024]: n<64 W_xp, 64..79 W_Bg, 80..95 W_Cg, else 0 ----
__global__ __launch_bounds__(256)
void build_wg(const float* __restrict__ W_xp, const float* __restrict__ W_Bg,
              const float* __restrict__ W_Cg, unsigned short* __restrict__ WgT) {
    int idx = blockIdx.x * 256 + threadIdx.x;   // [n][k], k fastest
    int k = idx & 1023, n = idx >> 10;
    float v = 0.0f;
    if (n < 64)       v = W_xp[k * RK + n];
    else if (n < 80)  v = W_Bg[k * DS + (n - 64)];
    else if (n < 96)  v = W_Cg[k * DS + (n - 80)];
    WgT[idx] = f2bf(v);
}

// ---- pack WupT[3072][128]: block-diag(W_dt, W_Bp, W_Cp) ----
__global__ __launch_bounds__(256)
void build_wup(const float* __restrict__ W_dt, const float* __restrict__ W_Bp,
               const float* __restrict__ W_Cp, unsigned short* __restrict__ WupT) {
    int idx = blockIdx.x * 256 + threadIdx.x;   // [n][k], k fastest
    int k = idx & 127, n = idx >> 7;
    float v = 0.0f;
    if (n < 1024)      { if (k < 64)            v = W_dt[k * 1024 + n]; }
    else if (n < 2048) { if (k >= 64 && k < 80) v = W_Bp[(k - 64) * 1024 + (n - 1024)]; }
    else               { if (k >= 80 && k < 96) v = W_Cp[(k - 80) * 1024 + (n - 2048)]; }
    WupT[idx] = f2bf(v);
}

// ======== 256x256 8-wave pipelined MFMA GEMM (T1+T2+T3+T4+T5) ========
// C[M,N] = A[M,K] @ BT[N,K]^T.  BK=64, dbuf LDS 128 KiB, counted vmcnt(2).
// EPI 1: split bf16 store cols [0,DD)->C0, [DD,2DD)->C1 (ld=DD)
// EPI 2: f32 store = acc + res (ld=N)
#define MF(a, b, c) __builtin_amdgcn_mfma_f32_16x16x32_bf16(a, b, c, 0, 0, 0)
template<int EPI>
__global__ __launch_bounds__(512, 1)
void gemm256(const unsigned short* __restrict__ A, const unsigned short* __restrict__ BT,
             void* __restrict__ C0v, void* __restrict__ C1v,
             const float* __restrict__ res, int M, int N, int K) {
    extern __shared__ unsigned short sm[];
    unsigned short* As = sm;            // [2][256*64] ushorts (32 KiB per buf)
    unsigned short* Bs = sm + 32768;
    const int tid = threadIdx.x;
    const int wave = tid >> 6, lane = tid & 63;
    const int wr = wave >> 2, wc = wave & 3;       // 2 x 4 waves
    const int fr = lane & 15, fs = lane >> 4;      // frag row / k-seg

    // T1: bijective XCD swizzle (grids here always have nwg % 8 == 0)
    int nbx = gridDim.x;
    int nwg = nbx * gridDim.y;
    int bid = blockIdx.y * nbx + blockIdx.x;
    int cpx = nwg >> 3;
    int swz = (bid & 7) * cpx + (bid >> 3);
    int by = swz / nbx, bx = swz - by * nbx;
    size_t rb = (size_t)by * 256, cb = (size_t)bx * 256;

    // staging: round covers 64 rows; thread -> (row = rnd*64 + tid>>3, seg = tid&7)
    // T2 both-sides swizzle: source seg pre-XORed, LDS dest linear (rule 21)
    const int srow = tid >> 3;
    const int ssw  = (tid & 7) ^ (srow & 7);
    const unsigned short* gA = A + (rb + srow) * K + ssw * 8;
    const unsigned short* gB = BT + (cb + srow) * K + ssw * 8;
    const size_t rstep = (size_t)64 * K;
    unsigned short* dA = As + tid * 8;
    unsigned short* dB = Bs + tid * 8;
    const int T = K >> 6;

#define STG(rnd, buf, kt) do { \
    gload16(gA + (size_t)(rnd) * rstep + (size_t)(kt) * 64, dA + (buf) * 16384 + (rnd) * 4096); \
    gload16(gB + (size_t)(rnd) * rstep + (size_t)(kt) * 64, dB + (buf) * 16384 + (rnd) * 4096); } while (0)
    // read side: logical (row r, seg S) lives at r*64 + ((S ^ (r&7))<<3)
#define FOFF(r, S) (((r) << 6) + ((((S) ^ ((r) & 7))) << 3))
#define LDA(i, kk) (*(const short8*)&Ab[FOFF(arow0 + ((i) << 4), fs + ((kk) << 2))])
#define LDB(j, kk) (*(const short8*)&Bb[FOFF(brow0 + ((j) << 4), fs + ((kk) << 2))])

    const int arow0 = wr * 128 + fr;
    const int brow0 = wc * 64 + fr;

    f32x4 acc[8][4] = {};

    // prologue: tile 0 -> buf 0 (8 loads per wave)
    STG(0, 0, 0); STG(1, 0, 0); STG(2, 0, 0); STG(3, 0, 0);

    #pragma unroll 1
    for (int t = 0; t < T; ++t) {
        const int cur = t & 1, nx = cur ^ 1;
        const bool pf = (t + 1) < T;
        const unsigned short* Ab = As + cur * 16384;
        const unsigned short* Bb = Bs + cur * 16384;

        // ---- phase 0: issue stage, counted wait, barrier, B-frags + m_rep 0-1
        if (pf) { STG(0, nx, t + 1); }
        if (pf) { asm volatile("s_waitcnt vmcnt(2)" ::: "memory"); }
        else    { asm volatile("s_waitcnt vmcnt(0)" ::: "memory"); }
        __builtin_amdgcn_s_barrier();
        __builtin_amdgcn_sched_barrier(0);

        short8 bfr[4][2];
        #pragma unroll
        for (int j = 0; j < 4; ++j) {
            bfr[j][0] = LDB(j, 0);
            bfr[j][1] = LDB(j, 1);
        }
        __builtin_amdgcn_s_setprio(1);
        #pragma unroll
        for (int ii = 0; ii < 2; ++ii) {
            short8 a0 = LDA(ii, 0), a1 = LDA(ii, 1);
            #pragma unroll
            for (int j = 0; j < 4; ++j) {
                acc[ii][j] = MF(a0, bfr[j][0], acc[ii][j]);
                acc[ii][j] = MF(a1, bfr[j][1], acc[ii][j]);
            }
        }
        __builtin_amdgcn_s_setprio(0);
        __builtin_amdgcn_sched_barrier(0);

        // ---- phases 1..3: stage + m_rep 2p..2p+1
        #pragma unroll
        for (int p = 1; p < 4; ++p) {
            if (pf) { STG(p, nx, t + 1); }
            __builtin_amdgcn_s_setprio(1);
            #pragma unroll
            for (int ii = 0; ii < 2; ++ii) {
                const int i = 2 * p + ii;
                short8 a0 = LDA(i, 0), a1 = LDA(i, 1);
                #pragma unroll
                for (int j = 0; j < 4; ++j) {
                    acc[i][j] = MF(a0, bfr[j][0], acc[i][j]);
                    acc[i][j] = MF(a1, bfr[j][1], acc[i][j]);
                }
            }
            __builtin_amdgcn_s_setprio(0);
            __builtin_amdgcn_sched_barrier(0);
        }
        __builtin_amdgcn_s_barrier();
    }

    // epilogue: C/D layout col = lane&15, row = (lane>>4)*4 + reg
    const int row0 = (int)rb + wr * 128 + fs * 4;
    const int col0 = (int)cb + wc * 64 + fr;
    if (EPI == 1) {
        unsigned short* Cd = (cb < DD) ? (unsigned short*)C0v : (unsigned short*)C1v;
        const int cadj = (cb < DD) ? 0 : -DD;
        #pragma unroll
        for (int i = 0; i < 8; ++i)
            #pragma unroll
            for (int j = 0; j < 4; ++j) {
                int col = col0 + cadj + (j << 4);
                #pragma unroll
                for (int q = 0; q < 4; ++q)
                    Cd[(size_t)(row0 + (i << 4) + q) * DD + col] = f2bf(acc[i][j][q]);
            }
    } else {
        float* C0 = (float*)C0v;
        #pragma unroll
        for (int i = 0; i < 8; ++i)
            #pragma unroll
            for (int j = 0; j < 4; ++j) {
                int col = col0 + (j << 4);
                #pragma unroll
                for (int q = 0; q < 4; ++q) {
                    size_t off = (size_t)(row0 + (i << 4) + q) * N + col;
                    C0[off] = acc[i][j][q] + res[off];
                }
            }
    }
#undef STG
#undef FOFF
#undef LDA
#undef LDB
}

// ---------------- m97-style 128x128 MFMA GEMM (short-K cases) ----------------
// EPI 0: bf16 store, ld=N.  EPI 3: f32 split-K partial (blockIdx.z slice)
template<int EPI>
__global__ __launch_bounds__(256)
void gemm_mfma(const unsigned short* __restrict__ A, const unsigned short* __restrict__ BT,
               void* __restrict__ C0v, void* __restrict__ C1v,
               const float* __restrict__ res, int M, int N, int K) {
    __shared__ unsigned short As[128 * 32];
    __shared__ unsigned short Bs[128 * 32];
    int tid = threadIdx.x;
    int rb = blockIdx.y * 128, cb = blockIdx.x * 128;
    int wave = tid >> 6, lane = tid & 63;
    int wr = wave >> 1, wc = wave & 1;
    int fr = lane & 15, fs = lane >> 4;

    int r0 = tid >> 2, s0 = tid & 3;
    int sw0 = s0 ^ ((r0 >> 1) & 3);
    const unsigned short* gA = A + (size_t)(rb + r0) * K + sw0 * 8;
    const unsigned short* gB = BT + (size_t)(cb + r0) * K + sw0 * 8;
    size_t half = (size_t)64 * K;
    char* lA0 = (char*)As + tid * 16;
    char* lA1 = (char*)As + (tid + 256) * 16;
    char* lB0 = (char*)Bs + tid * 16;
    char* lB1 = (char*)Bs + (tid + 256) * 16;

    int kb = 0, ke = K;
    if (EPI == 3) { kb = blockIdx.z * (K >> 2); ke = kb + (K >> 2); }

    f32x4 acc[4][4] = {};

    #pragma unroll 1
    for (int k0 = kb; k0 < ke; k0 += 32) {
        __syncthreads();
        gload16(gA + k0, lA0);
        gload16(gA + half + k0, lA1);
        gload16(gB + k0, lB0);
        gload16(gB + half + k0, lB1);
        __syncthreads();

        short8 af[4], bfr[4];
        #pragma unroll
        for (int i = 0; i < 4; i++) {
            int row = (wr << 6) + (i << 4) + fr;
            int off = (row << 5) + ((fs ^ ((row >> 1) & 3)) << 3);
            af[i] = *(const short8*)&As[off];
        }
        #pragma unroll
        for (int j = 0; j < 4; j++) {
            int row = (wc << 6) + (j << 4) + fr;
            int off = (row << 5) + ((fs ^ ((row >> 1) & 3)) << 3);
            bfr[j] = *(const short8*)&Bs[off];
        }
        #pragma unroll
        for (int i = 0; i < 4; i++)
            #pragma unroll
            for (int j = 0; j < 4; j++)
                acc[i][j] = MF(af[i], bfr[j], acc[i][j]);
    }

    int row0 = rb + (wr << 6) + (fs << 2);
    int col0 = (wc << 6) + fr;
    if (EPI == 0) {
        unsigned short* C0 = (unsigned short*)C0v;
        #pragma unroll
        for (int i = 0; i < 4; i++)
            #pragma unroll
            for (int j = 0; j < 4; j++) {
                int col = cb + col0 + (j << 4);
                #pragma unroll
                for (int q = 0; q < 4; q++)
                    C0[(size_t)(row0 + (i << 4) + q) * N + col] = f2bf(acc[i][j][q]);
            }
    } else {
        float* C0 = (float*)C0v + (size_t)blockIdx.z * M * N;
        #pragma unroll
        for (int i = 0; i < 4; i++)
            #pragma unroll
            for (int j = 0; j < 4; j++) {
                int col = cb + col0 + (j << 4);
                #pragma unroll
                for (int q = 0; q < 4; q++)
                    C0[(size_t)(row0 + (i << 4) + q) * N + col] = acc[i][j][q];
            }
    }
}

// ---- reduce 4 split-K partials (f32) -> bf16 t ----
__global__ __launch_bounds__(256)
void reduce_t(const float* __restrict__ tp, unsigned short* __restrict__ t_bf) {
    int idx = blockIdx.x * 256 + threadIdx.x;
    const size_t Q = (size_t)MM * 128 / 4;
    float4 a = ((const float4*)tp)[idx];
    float4 b = ((const float4*)tp)[idx + Q];
    float4 c = ((const float4*)tp)[idx + 2 * Q];
    float4 d = ((const float4*)tp)[idx + 3 * Q];
    ushort4 o;
    o.x = f2bf(a.x + b.x + c.x + d.x);
    o.y = f2bf(a.y + b.y + c.y + d.y);
    o.z = f2bf(a.z + b.z + c.z + d.z);
    o.w = f2bf(a.w + b.w + c.w + d.w);
    ((ushort4*)t_bf)[idx] = o;
}

// ---------------- depthwise conv1d (K=3, SAME) + SiLU, bf16 in/out ----------------
__global__ __launch_bounds__(256)
void conv_silu(const unsigned short* __restrict__ xb, const float* __restrict__ cw,
               const float* __restrict__ cb, unsigned short* __restrict__ xact) {
    int idx8 = blockIdx.x * 256 + threadIdx.x;
    size_t e = (size_t)idx8 * 8;
    int d0 = (int)(e & (DD - 1));
    int bl = (int)(e >> 10);
    int l = bl & (LL - 1);
    short8 cur = *(const short8*)&xb[e];
    short8 prv = {}, nxt = {};
    if (l > 0)      prv = *(const short8*)&xb[e - DD];
    if (l < LL - 1) nxt = *(const short8*)&xb[e + DD];
    short8 o;
    #pragma unroll
    for (int j = 0; j < 8; j++) {
        int d = d0 + j;
        float acc = cb[d];
        acc = fmaf(bf2f((unsigned short)prv[j]), cw[0 * DD + d], acc);
        acc = fmaf(bf2f((unsigned short)cur[j]), cw[1 * DD + d], acc);
        acc = fmaf(bf2f((unsigned short)nxt[j]), cw[2 * DD + d], acc);
        float s = acc / (1.0f + expf(-acc));
        o[j] = (short)f2bf(s);
    }
    *(short8*)&xact[e] = o;
}

// ---------------- selective scan, chunked; params from dBC (bf16, ld=3072) ----------------
__global__ __launch_bounds__(256)
void scan_p1(const unsigned short* __restrict__ dbc, const unsigned short* __restrict__ xact,
             const float* __restrict__ b_dt, const float* __restrict__ A,
             float* __restrict__ P, float* __restrict__ Hc) {
    int d = blockIdx.x * 256 + threadIdx.x;
    int c = blockIdx.y, b = blockIdx.z;
    float a_d = A[d], bd = b_dt[d];
    size_t row0 = (size_t)(b * LL + c * LC);
    float h = 0.0f, p = 1.0f;
    for (int i = 0; i < LC; i++) {
        size_t r = row0 + i;
        size_t o3 = r * 3072 + d;
        float dl = softplusf(bf2f(dbc[o3]) + bd);
        float bm = bf2f(dbc[o3 + 1024]);
        float xa = bf2f(xact[r * DD + d]);
        float a = expf(dl * a_d);
        h = fmaf(a, h, dl * bm * xa);
        p *= a;
    }
    int pc = (b * NC + c) * DD + d;
    P[pc] = p;
    Hc[pc] = h;
}

__global__ __launch_bounds__(256)
void scan_p2(const float* __restrict__ P, const float* __restrict__ Hc,
             float* __restrict__ hin) {
    int d = blockIdx.x * 256 + threadIdx.x;
    int b = blockIdx.y;
    float carry = 0.0f;
    for (int c = 0; c < NC; c++) {
        int o = (b * NC + c) * DD + d;
        hin[o] = carry;
        carry = fmaf(P[o], carry, Hc[o]);
    }
}

__global__ __launch_bounds__(256)
void scan_p3(const unsigned short* __restrict__ dbc, const unsigned short* __restrict__ xact,
             const unsigned short* __restrict__ zb, const float* __restrict__ hin,
             const float* __restrict__ b_dt, const float* __restrict__ A,
             const float* __restrict__ Dsk, unsigned short* __restrict__ g) {
    int d = blockIdx.x * 256 + threadIdx.x;
    int c = blockIdx.y, b = blockIdx.z;
    float a_d = A[d], bd = b_dt[d], dskip = Dsk[d];
    float h = hin[(b * NC + c) * DD + d];
    size_t row0 = (size_t)(b * LL + c * LC);
    for (int i = 0; i < LC; i++) {
        size_t r = row0 + i;
        size_t o3 = r * 3072 + d;
        size_t o = r * DD + d;
        float dl = softplusf(bf2f(dbc[o3]) + bd);
        float bm = bf2f(dbc[o3 + 1024]);
        float cm = bf2f(dbc[o3 + 2048]);
        float xa = bf2f(xact[o]);
        float a = expf(dl * a_d);
        h = fmaf(a, h, dl * bm * xa);
        float y = cm * h;
        float os = fmaf(xa, dskip, y);
        float zv = bf2f(zb[o]);
        g[o] = f2bf(os * (zv / (1.0f + expf(-zv))));
    }
}

extern "C" void kernel_launch(void* const* d_in, const int* in_sizes, int n_in,
                              void* d_out, int out_size, void* d_ws, size_t ws_size,
                              hipStream_t stream) {
    const float* x      = (const float*)d_in[0];
    const float* gamma  = (const float*)d_in[1];
    const float* beta   = (const float*)d_in[2];
    const float* W_in   = (const float*)d_in[3];
    const float* conv_w = (const float*)d_in[4];
    const float* conv_b = (const float*)d_in[5];
    const float* W_xp   = (const float*)d_in[6];
    const float* W_Bg   = (const float*)d_in[7];
    const float* W_Cg   = (const float*)d_in[8];
    const float* W_dt   = (const float*)d_in[9];
    const float* b_dt   = (const float*)d_in[10];
    const float* W_Bp   = (const float*)d_in[11];
    const float* W_Cp   = (const float*)d_in[12];
    const float* A      = (const float*)d_in[13];
    const float* Dsk    = (const float*)d_in[14];
    const float* W_out  = (const float*)d_in[15];
    float* out = (float*)d_out;

    const size_t BIG = (size_t)MM * DD;
    char* p = (char*)d_ws;
    unsigned short* xn_bf  = (unsigned short*)p;  p += BIG * 2;       // reused as g
    unsigned short* xb_bf  = (unsigned short*)p;  p += BIG * 2;
    unsigned short* z_bf   = (unsigned short*)p;  p += BIG * 2;
    unsigned short* xact_bf= (unsigned short*)p;  p += BIG * 2;
    unsigned short* t_bf   = (unsigned short*)p;  p += (size_t)MM * 128 * 2;
    unsigned short* dBC    = (unsigned short*)p;  p += (size_t)MM * 3072 * 2;
    float* tpart = (float*)p;                     p += (size_t)4 * MM * 128 * 4;
    float* P     = (float*)p;                     p += (size_t)BB * NC * DD * 4;
    float* Hc    = (float*)p;                     p += (size_t)BB * NC * DD * 4;
    float* hin   = (float*)p;                     p += (size_t)BB * NC * DD * 4;
    unsigned short* WinT  = (unsigned short*)p;   p += (size_t)2 * DD * DD * 2;
    unsigned short* WoutT = (unsigned short*)p;   p += (size_t)DD * DD * 2;
    unsigned short* WgT   = (unsigned short*)p;   p += (size_t)128 * DD * 2;
    unsigned short* WupT  = (unsigned short*)p;   p += (size_t)3072 * 128 * 2;
    unsigned short* g_bf  = xn_bf;

    // allow 128 KiB dynamic LDS for gemm256 (defensive; ignore errors)
    {
        void (*k1)(const unsigned short*, const unsigned short*, void*, void*,
                   const float*, int, int, int) = gemm256<1>;
        void (*k2)(const unsigned short*, const unsigned short*, void*, void*,
                   const float*, int, int, int) = gemm256<2>;
        (void)hipFuncSetAttribute((const void*)k1,
            hipFuncAttributeMaxDynamicSharedMemorySize, 131072);
        (void)hipFuncSetAttribute((const void*)k2,
            hipFuncAttributeMaxDynamicSharedMemorySize, 131072);
    }

    // 0. weight prep
    transpose_bf16<<<dim3(2 * DD / 32, DD / 32), 256, 0, stream>>>(W_in, WinT, DD, 2 * DD);
    transpose_bf16<<<dim3(DD / 32, DD / 32), 256, 0, stream>>>(W_out, WoutT, DD, DD);
    build_wg<<<(128 * DD) / 256, 256, 0, stream>>>(W_xp, W_Bg, W_Cg, WgT);
    build_wup<<<(3072 * 128) / 256, 256, 0, stream>>>(W_dt, W_Bp, W_Cp, WupT);
    // 1. LayerNorm
    ln_kernel<<<MM, 256, 0, stream>>>(x, gamma, beta, xn_bf);
    // 2. in_proj -> xb | z (bf16), 256^2 pipelined
    gemm256<1><<<dim3(2 * DD / 256, MM / 256), 512, 131072, stream>>>(
        xn_bf, WinT, xb_bf, z_bf, nullptr, MM, 2 * DD, DD);
    // 3. depthwise conv + SiLU
    conv_silu<<<(MM * DD / 8) / 256, 256, 0, stream>>>(xb_bf, conv_w, conv_b, xact_bf);
    // 4a. down-proj (split-K=4) + reduce -> t (M x 128 bf16)
    gemm_mfma<3><<<dim3(1, MM / 128, 4), 256, 0, stream>>>(
        xact_bf, WgT, tpart, nullptr, nullptr, MM, 128, DD);
    reduce_t<<<(MM * 128 / 4) / 256, 256, 0, stream>>>(tpart, t_bf);
    // 4b. up-proj -> dBC = [delta_raw | Bm | Cm] (M x 3072 bf16)
    gemm_mfma<0><<<dim3(3072 / 128, MM / 128), 256, 0, stream>>>(
        t_bf, WupT, dBC, nullptr, nullptr, MM, 3072, 128);
    // 5. chunked selective scan + gating
    scan_p1<<<dim3(DD / 256, NC, BB), 256, 0, stream>>>(dBC, xact_bf, b_dt, A, P, Hc);
    scan_p2<<<dim3(DD / 256, BB), 256, 0, stream>>>(P, Hc, hin);
    scan_p3<<<dim3(DD / 256, NC, BB), 256, 0, stream>>>(dBC, xact_bf, z_bf, hin,
                                                        b_dt, A, Dsk, g_bf);
    // 6. out_proj + residual (f32 out), 256^2 pipelined
    gemm256<2><<<dim3(DD / 256, MM / 256), 512, 131072, stream>>>(
        g_bf, WoutT, out, nullptr, x, MM, DD, DD);
}

// Round 5
// 184.959 us; speedup vs baseline: 6.9387x; 1.3010x over previous
//
#include <hip/hip_runtime.h>
#include <math.h>

#define BB 2
#define LL 4096
#define DD 1024
#define DS 16
#define RK 64
#define MM (BB*LL)        // 8192
#define NC 128            // scan chunks
#define LC (LL/NC)        // 32

typedef __attribute__((ext_vector_type(8))) short short8;
typedef __attribute__((ext_vector_type(4))) float f32x4;

__device__ __forceinline__ unsigned short f2bf(float f) {
    union { float f; unsigned u; } v; v.f = f;
    unsigned r = v.u + 0x7fff + ((v.u >> 16) & 1);
    return (unsigned short)(r >> 16);
}
__device__ __forceinline__ float bf2f(unsigned short u) {
    union { unsigned u; float f; } v; v.u = ((unsigned)u) << 16;
    return v.f;
}
__device__ __forceinline__ float2 bf2x2(unsigned u) {
    return make_float2(bf2f((unsigned short)u), bf2f((unsigned short)(u >> 16)));
}
__device__ __forceinline__ unsigned f2bfx2(float lo, float hi) {
    return (unsigned)f2bf(lo) | ((unsigned)f2bf(hi) << 16);
}
__device__ __forceinline__ float fast_rcp(float x) {
    return __builtin_amdgcn_rcpf(x);
}
__device__ __forceinline__ float silu_f(float v) {      // v * sigmoid(v), fast
    return v * fast_rcp(1.0f + __expf(-v));
}
__device__ __forceinline__ void gload16(const void* g, void* l) {
    __builtin_amdgcn_global_load_lds(
        (const __attribute__((address_space(1))) unsigned int*)g,
        (__attribute__((address_space(3))) unsigned int*)l, 16, 0, 0);
}

// ---------------- LayerNorm -> bf16 ----------------
__global__ __launch_bounds__(256)
void ln_kernel(const float* __restrict__ x, const float* __restrict__ gamma,
               const float* __restrict__ beta, unsigned short* __restrict__ xn_bf) {
    int row = blockIdx.x;
    int tid = threadIdx.x;
    const float4* xr = (const float4*)(x + (size_t)row * DD);
    float4 v = xr[tid];
    float s = v.x + v.y + v.z + v.w;
    float q = v.x*v.x + v.y*v.y + v.z*v.z + v.w*v.w;
    #pragma unroll
    for (int off = 32; off > 0; off >>= 1) {
        s += __shfl_down(s, off);
        q += __shfl_down(q, off);
    }
    __shared__ float ss[4], qq[4];
    int wv = tid >> 6;
    if ((tid & 63) == 0) { ss[wv] = s; qq[wv] = q; }
    __syncthreads();
    float S = ss[0] + ss[1] + ss[2] + ss[3];
    float Q = qq[0] + qq[1] + qq[2] + qq[3];
    float mu  = S * (1.0f / DD);
    float var = Q * (1.0f / DD) - mu * mu;
    float r = rsqrtf(var + 1e-5f);
    int d0 = tid * 4;
    float4 gv = *(const float4*)(gamma + d0);
    float4 bv = *(const float4*)(beta + d0);
    ushort4 o;
    o.x = f2bf((v.x - mu) * r * gv.x + bv.x);
    o.y = f2bf((v.y - mu) * r * gv.y + bv.y);
    o.z = f2bf((v.z - mu) * r * gv.z + bv.z);
    o.w = f2bf((v.w - mu) * r * gv.w + bv.w);
    *(ushort4*)&xn_bf[(size_t)row * DD + d0] = o;
}

// ---------------- f32 [K][N] -> bf16 [N][K] transpose-convert ----------------
__global__ __launch_bounds__(256)
void transpose_bf16(const float* __restrict__ W, unsigned short* __restrict__ WT,
                    int K, int N) {
    __shared__ float t[32][33];
    int n0 = blockIdx.x * 32, k0 = blockIdx.y * 32;
    int tx = threadIdx.x & 31, ty = threadIdx.x >> 5;   // 32 x 8
    #pragma unroll
    for (int r = 0; r < 32; r += 8)
        t[ty + r][tx] = W[(size_t)(k0 + ty + r) * N + n0 + tx];
    __syncthreads();
    #pragma unroll
    for (int r = 0; r < 32; r += 8) {
        int nl = ty + r;
        WT[(size_t)(n0 + nl) * K + k0 + tx] = f2bf(t[tx][nl]);
    }
}

// ---- pack WgT[128][1024]: n<64 W_xp, 64..79 W_Bg, 80..95 W_Cg, else 0 ----
__global__ __launch_bounds__(256)
void build_wg(const float* __restrict__ W_xp, const float* __restrict__ W_Bg,
              const float* __restrict__ W_Cg, unsigned short* __restrict__ WgT) {
    int idx = blockIdx.x * 256 + threadIdx.x;   // [n][k], k fastest
    int k = idx & 1023, n = idx >> 10;
    float v = 0.0f;
    if (n < 64)       v = W_xp[k * RK + n];
    else if (n < 80)  v = W_Bg[k * DS + (n - 64)];
    else if (n < 96)  v = W_Cg[k * DS + (n - 80)];
    WgT[idx] = f2bf(v);
}

// ---- pack WupT[3072][128]: block-diag(W_dt, W_Bp, W_Cp) ----
__global__ __launch_bounds__(256)
void build_wup(const float* __restrict__ W_dt, const float* __restrict__ W_Bp,
               const float* __restrict__ W_Cp, unsigned short* __restrict__ WupT) {
    int idx = blockIdx.x * 256 + threadIdx.x;   // [n][k], k fastest
    int k = idx & 127, n = idx >> 7;
    float v = 0.0f;
    if (n < 1024)      { if (k < 64)            v = W_dt[k * 1024 + n]; }
    else if (n < 2048) { if (k >= 64 && k < 80) v = W_Bp[(k - 64) * 1024 + (n - 1024)]; }
    else               { if (k >= 80 && k < 96) v = W_Cp[(k - 80) * 1024 + (n - 2048)]; }
    WupT[idx] = f2bf(v);
}

// ======== 256x256 8-wave pipelined MFMA GEMM (T1+T2+T3+T4+T5) ========
#define MF(a, b, c) __builtin_amdgcn_mfma_f32_16x16x32_bf16(a, b, c, 0, 0, 0)
template<int EPI>
__global__ __launch_bounds__(512, 1)
void gemm256(const unsigned short* __restrict__ A, const unsigned short* __restrict__ BT,
             void* __restrict__ C0v, void* __restrict__ C1v,
             const float* __restrict__ res, int M, int N, int K) {
    extern __shared__ unsigned short sm[];
    unsigned short* As = sm;            // [2][256*64] ushorts (32 KiB per buf)
    unsigned short* Bs = sm + 32768;
    const int tid = threadIdx.x;
    const int wave = tid >> 6, lane = tid & 63;
    const int wr = wave >> 2, wc = wave & 3;       // 2 x 4 waves
    const int fr = lane & 15, fs = lane >> 4;

    int nbx = gridDim.x;
    int nwg = nbx * gridDim.y;
    int bid = blockIdx.y * nbx + blockIdx.x;
    int cpx = nwg >> 3;
    int swz = (bid & 7) * cpx + (bid >> 3);
    int by = swz / nbx, bx = swz - by * nbx;
    size_t rb = (size_t)by * 256, cb = (size_t)bx * 256;

    const int srow = tid >> 3;
    const int ssw  = (tid & 7) ^ (srow & 7);
    const unsigned short* gA = A + (rb + srow) * K + ssw * 8;
    const unsigned short* gB = BT + (cb + srow) * K + ssw * 8;
    const size_t rstep = (size_t)64 * K;
    unsigned short* dA = As + tid * 8;
    unsigned short* dB = Bs + tid * 8;
    const int T = K >> 6;

#define STG(rnd, buf, kt) do { \
    gload16(gA + (size_t)(rnd) * rstep + (size_t)(kt) * 64, dA + (buf) * 16384 + (rnd) * 4096); \
    gload16(gB + (size_t)(rnd) * rstep + (size_t)(kt) * 64, dB + (buf) * 16384 + (rnd) * 4096); } while (0)
#define FOFF(r, S) (((r) << 6) + ((((S) ^ ((r) & 7))) << 3))
#define LDA(i, kk) (*(const short8*)&Ab[FOFF(arow0 + ((i) << 4), fs + ((kk) << 2))])
#define LDB(j, kk) (*(const short8*)&Bb[FOFF(brow0 + ((j) << 4), fs + ((kk) << 2))])

    const int arow0 = wr * 128 + fr;
    const int brow0 = wc * 64 + fr;

    f32x4 acc[8][4] = {};

    STG(0, 0, 0); STG(1, 0, 0); STG(2, 0, 0); STG(3, 0, 0);

    #pragma unroll 1
    for (int t = 0; t < T; ++t) {
        const int cur = t & 1, nx = cur ^ 1;
        const bool pf = (t + 1) < T;
        const unsigned short* Ab = As + cur * 16384;
        const unsigned short* Bb = Bs + cur * 16384;

        if (pf) { STG(0, nx, t + 1); }
        if (pf) { asm volatile("s_waitcnt vmcnt(2)" ::: "memory"); }
        else    { asm volatile("s_waitcnt vmcnt(0)" ::: "memory"); }
        __builtin_amdgcn_s_barrier();
        __builtin_amdgcn_sched_barrier(0);

        short8 bfr[4][2];
        #pragma unroll
        for (int j = 0; j < 4; ++j) {
            bfr[j][0] = LDB(j, 0);
            bfr[j][1] = LDB(j, 1);
        }
        __builtin_amdgcn_s_setprio(1);
        #pragma unroll
        for (int ii = 0; ii < 2; ++ii) {
            short8 a0 = LDA(ii, 0), a1 = LDA(ii, 1);
            #pragma unroll
            for (int j = 0; j < 4; ++j) {
                acc[ii][j] = MF(a0, bfr[j][0], acc[ii][j]);
                acc[ii][j] = MF(a1, bfr[j][1], acc[ii][j]);
            }
        }
        __builtin_amdgcn_s_setprio(0);
        __builtin_amdgcn_sched_barrier(0);

        #pragma unroll
        for (int p = 1; p < 4; ++p) {
            if (pf) { STG(p, nx, t + 1); }
            __builtin_amdgcn_s_setprio(1);
            #pragma unroll
            for (int ii = 0; ii < 2; ++ii) {
                const int i = 2 * p + ii;
                short8 a0 = LDA(i, 0), a1 = LDA(i, 1);
                #pragma unroll
                for (int j = 0; j < 4; ++j) {
                    acc[i][j] = MF(a0, bfr[j][0], acc[i][j]);
                    acc[i][j] = MF(a1, bfr[j][1], acc[i][j]);
                }
            }
            __builtin_amdgcn_s_setprio(0);
            __builtin_amdgcn_sched_barrier(0);
        }
        __builtin_amdgcn_s_barrier();
    }

    const int row0 = (int)rb + wr * 128 + fs * 4;
    const int col0 = (int)cb + wc * 64 + fr;
    if (EPI == 1) {
        unsigned short* Cd = (cb < DD) ? (unsigned short*)C0v : (unsigned short*)C1v;
        const int cadj = (cb < DD) ? 0 : -DD;
        #pragma unroll
        for (int i = 0; i < 8; ++i)
            #pragma unroll
            for (int j = 0; j < 4; ++j) {
                int col = col0 + cadj + (j << 4);
                #pragma unroll
                for (int q = 0; q < 4; ++q)
                    Cd[(size_t)(row0 + (i << 4) + q) * DD + col] = f2bf(acc[i][j][q]);
            }
    } else {
        float* C0 = (float*)C0v;
        #pragma unroll
        for (int i = 0; i < 8; ++i)
            #pragma unroll
            for (int j = 0; j < 4; ++j) {
                int col = col0 + (j << 4);
                #pragma unroll
                for (int q = 0; q < 4; ++q) {
                    size_t off = (size_t)(row0 + (i << 4) + q) * N + col;
                    C0[off] = acc[i][j][q] + res[off];
                }
            }
    }
#undef STG
#undef FOFF
#undef LDA
#undef LDB
}

// ---------------- m97-style 128x128 MFMA GEMM (short-K cases) ----------------
// EPI 0: bf16 store, ld=N.  EPI 3: f32 split-K partial (blockIdx.z slice)
// EPI 4: bf16 store; cols < DD get softplus(acc + bias[col])  (up-proj delta)
template<int EPI>
__global__ __launch_bounds__(256)
void gemm_mfma(const unsigned short* __restrict__ A, const unsigned short* __restrict__ BT,
               void* __restrict__ C0v, void* __restrict__ C1v,
               const float* __restrict__ res, int M, int N, int K) {
    __shared__ unsigned short As[128 * 32];
    __shared__ unsigned short Bs[128 * 32];
    int tid = threadIdx.x;
    int rb = blockIdx.y * 128, cb = blockIdx.x * 128;
    int wave = tid >> 6, lane = tid & 63;
    int wr = wave >> 1, wc = wave & 1;
    int fr = lane & 15, fs = lane >> 4;

    int r0 = tid >> 2, s0 = tid & 3;
    int sw0 = s0 ^ ((r0 >> 1) & 3);
    const unsigned short* gA = A + (size_t)(rb + r0) * K + sw0 * 8;
    const unsigned short* gB = BT + (size_t)(cb + r0) * K + sw0 * 8;
    size_t half = (size_t)64 * K;
    char* lA0 = (char*)As + tid * 16;
    char* lA1 = (char*)As + (tid + 256) * 16;
    char* lB0 = (char*)Bs + tid * 16;
    char* lB1 = (char*)Bs + (tid + 256) * 16;

    int kb = 0, ke = K;
    if (EPI == 3) { kb = blockIdx.z * (K >> 2); ke = kb + (K >> 2); }

    f32x4 acc[4][4] = {};

    #pragma unroll 1
    for (int k0 = kb; k0 < ke; k0 += 32) {
        __syncthreads();
        gload16(gA + k0, lA0);
        gload16(gA + half + k0, lA1);
        gload16(gB + k0, lB0);
        gload16(gB + half + k0, lB1);
        __syncthreads();

        short8 af[4], bfr[4];
        #pragma unroll
        for (int i = 0; i < 4; i++) {
            int row = (wr << 6) + (i << 4) + fr;
            int off = (row << 5) + ((fs ^ ((row >> 1) & 3)) << 3);
            af[i] = *(const short8*)&As[off];
        }
        #pragma unroll
        for (int j = 0; j < 4; j++) {
            int row = (wc << 6) + (j << 4) + fr;
            int off = (row << 5) + ((fs ^ ((row >> 1) & 3)) << 3);
            bfr[j] = *(const short8*)&Bs[off];
        }
        #pragma unroll
        for (int i = 0; i < 4; i++)
            #pragma unroll
            for (int j = 0; j < 4; j++)
                acc[i][j] = MF(af[i], bfr[j], acc[i][j]);
    }

    int row0 = rb + (wr << 6) + (fs << 2);
    int col0 = (wc << 6) + fr;
    if (EPI == 0) {
        unsigned short* C0 = (unsigned short*)C0v;
        #pragma unroll
        for (int i = 0; i < 4; i++)
            #pragma unroll
            for (int j = 0; j < 4; j++) {
                int col = cb + col0 + (j << 4);
                #pragma unroll
                for (int q = 0; q < 4; q++)
                    C0[(size_t)(row0 + (i << 4) + q) * N + col] = f2bf(acc[i][j][q]);
            }
    } else if (EPI == 4) {
        unsigned short* C0 = (unsigned short*)C0v;
        const bool isdelta = (cb < DD);
        #pragma unroll
        for (int i = 0; i < 4; i++)
            #pragma unroll
            for (int j = 0; j < 4; j++) {
                int col = cb + col0 + (j << 4);
                float bias = isdelta ? res[col] : 0.0f;
                #pragma unroll
                for (int q = 0; q < 4; q++) {
                    float v = acc[i][j][q];
                    if (isdelta) {
                        v += bias;
                        v = fmaxf(v, 0.0f) + __logf(1.0f + __expf(-fabsf(v)));
                    }
                    C0[(size_t)(row0 + (i << 4) + q) * N + col] = f2bf(v);
                }
            }
    } else {
        float* C0 = (float*)C0v + (size_t)blockIdx.z * M * N;
        #pragma unroll
        for (int i = 0; i < 4; i++)
            #pragma unroll
            for (int j = 0; j < 4; j++) {
                int col = cb + col0 + (j << 4);
                #pragma unroll
                for (int q = 0; q < 4; q++)
                    C0[(size_t)(row0 + (i << 4) + q) * N + col] = acc[i][j][q];
            }
    }
}

// ---- reduce 4 split-K partials (f32) -> bf16 t ----
__global__ __launch_bounds__(256)
void reduce_t(const float* __restrict__ tp, unsigned short* __restrict__ t_bf) {
    int idx = blockIdx.x * 256 + threadIdx.x;
    const size_t Q = (size_t)MM * 128 / 4;
    float4 a = ((const float4*)tp)[idx];
    float4 b = ((const float4*)tp)[idx + Q];
    float4 c = ((const float4*)tp)[idx + 2 * Q];
    float4 d = ((const float4*)tp)[idx + 3 * Q];
    ushort4 o;
    o.x = f2bf(a.x + b.x + c.x + d.x);
    o.y = f2bf(a.y + b.y + c.y + d.y);
    o.z = f2bf(a.z + b.z + c.z + d.z);
    o.w = f2bf(a.w + b.w + c.w + d.w);
    ((ushort4*)t_bf)[idx] = o;
}

// ---------------- depthwise conv1d (K=3, SAME) + SiLU, bf16 in/out ----------------
__global__ __launch_bounds__(256)
void conv_silu(const unsigned short* __restrict__ xb, const float* __restrict__ cw,
               const float* __restrict__ cb, unsigned short* __restrict__ xact) {
    int idx8 = blockIdx.x * 256 + threadIdx.x;
    size_t e = (size_t)idx8 * 8;
    int d0 = (int)(e & (DD - 1));
    int bl = (int)(e >> 10);
    int l = bl & (LL - 1);
    short8 cur = *(const short8*)&xb[e];
    short8 prv = {}, nxt = {};
    if (l > 0)      prv = *(const short8*)&xb[e - DD];
    if (l < LL - 1) nxt = *(const short8*)&xb[e + DD];
    short8 o;
    #pragma unroll
    for (int j = 0; j < 8; j++) {
        int d = d0 + j;
        float acc = cb[d];
        acc = fmaf(bf2f((unsigned short)prv[j]), cw[0 * DD + d], acc);
        acc = fmaf(bf2f((unsigned short)cur[j]), cw[1 * DD + d], acc);
        acc = fmaf(bf2f((unsigned short)nxt[j]), cw[2 * DD + d], acc);
        o[j] = (short)f2bf(silu_f(acc));
    }
    *(short8*)&xact[e] = o;
}

// ---------------- selective scan, chunked, 2-wide; delta pre-softplus'd ----------------
__global__ __launch_bounds__(256)
void scan_p1(const unsigned short* __restrict__ dbc, const unsigned short* __restrict__ xact,
             const float* __restrict__ A, float* __restrict__ P, float* __restrict__ Hc) {
    int d = (blockIdx.x * 256 + threadIdx.x) * 2;
    int c = blockIdx.y, b = blockIdx.z;
    float2 a_d = *(const float2*)&A[d];
    size_t row0 = (size_t)(b * LL + c * LC);
    float h0 = 0.0f, h1 = 0.0f, sd0 = 0.0f, sd1 = 0.0f;
    #pragma unroll 4
    for (int i = 0; i < LC; i++) {
        size_t r = row0 + i;
        const unsigned short* pd = &dbc[r * 3072 + d];
        float2 dl = bf2x2(*(const unsigned*)pd);
        float2 bm = bf2x2(*(const unsigned*)(pd + 1024));
        float2 xa = bf2x2(*(const unsigned*)&xact[r * DD + d]);
        float a0 = __expf(dl.x * a_d.x);
        float a1 = __expf(dl.y * a_d.y);
        h0 = fmaf(a0, h0, dl.x * bm.x * xa.x);
        h1 = fmaf(a1, h1, dl.y * bm.y * xa.y);
        sd0 += dl.x; sd1 += dl.y;
    }
    int pc = (b * NC + c) * DD + d;
    *(float2*)&P[pc]  = make_float2(__expf(a_d.x * sd0), __expf(a_d.y * sd1));
    *(float2*)&Hc[pc] = make_float2(h0, h1);
}

__global__ __launch_bounds__(256)
void scan_p2(const float* __restrict__ P, const float* __restrict__ Hc,
             float* __restrict__ hin) {
    int d = blockIdx.x * 256 + threadIdx.x;
    int b = blockIdx.y;
    float carry = 0.0f;
    for (int c = 0; c < NC; c++) {
        int o = (b * NC + c) * DD + d;
        hin[o] = carry;
        carry = fmaf(P[o], carry, Hc[o]);
    }
}

__global__ __launch_bounds__(256)
void scan_p3(const unsigned short* __restrict__ dbc, const unsigned short* __restrict__ xact,
             const unsigned short* __restrict__ zb, const float* __restrict__ hin,
             const float* __restrict__ A, const float* __restrict__ Dsk,
             unsigned short* __restrict__ g) {
    int d = (blockIdx.x * 256 + threadIdx.x) * 2;
    int c = blockIdx.y, b = blockIdx.z;
    float2 a_d = *(const float2*)&A[d];
    float2 dsk = *(const float2*)&Dsk[d];
    float2 hv = *(const float2*)&hin[(b * NC + c) * DD + d];
    float h0 = hv.x, h1 = hv.y;
    size_t row0 = (size_t)(b * LL + c * LC);
    #pragma unroll 4
    for (int i = 0; i < LC; i++) {
        size_t r = row0 + i;
        const unsigned short* pd = &dbc[r * 3072 + d];
        float2 dl = bf2x2(*(const unsigned*)pd);
        float2 bm = bf2x2(*(const unsigned*)(pd + 1024));
        float2 cm = bf2x2(*(const unsigned*)(pd + 2048));
        size_t o = r * DD + d;
        float2 xa = bf2x2(*(const unsigned*)&xact[o]);
        float2 zv = bf2x2(*(const unsigned*)&zb[o]);
        float a0 = __expf(dl.x * a_d.x);
        float a1 = __expf(dl.y * a_d.y);
        h0 = fmaf(a0, h0, dl.x * bm.x * xa.x);
        h1 = fmaf(a1, h1, dl.y * bm.y * xa.y);
        float os0 = fmaf(xa.x, dsk.x, cm.x * h0);
        float os1 = fmaf(xa.y, dsk.y, cm.y * h1);
        float g0 = os0 * silu_f(zv.x);
        float g1 = os1 * silu_f(zv.y);
        *(unsigned*)&g[o] = f2bfx2(g0, g1);
    }
}

extern "C" void kernel_launch(void* const* d_in, const int* in_sizes, int n_in,
                              void* d_out, int out_size, void* d_ws, size_t ws_size,
                              hipStream_t stream) {
    const float* x      = (const float*)d_in[0];
    const float* gamma  = (const float*)d_in[1];
    const float* beta   = (const float*)d_in[2];
    const float* W_in   = (const float*)d_in[3];
    const float* conv_w = (const float*)d_in[4];
    const float* conv_b = (const float*)d_in[5];
    const float* W_xp   = (const float*)d_in[6];
    const float* W_Bg   = (const float*)d_in[7];
    const float* W_Cg   = (const float*)d_in[8];
    const float* W_dt   = (const float*)d_in[9];
    const float* b_dt   = (const float*)d_in[10];
    const float* W_Bp   = (const float*)d_in[11];
    const float* W_Cp   = (const float*)d_in[12];
    const float* A      = (const float*)d_in[13];
    const float* Dsk    = (const float*)d_in[14];
    const float* W_out  = (const float*)d_in[15];
    float* out = (float*)d_out;

    const size_t BIG = (size_t)MM * DD;
    char* p = (char*)d_ws;
    unsigned short* xn_bf  = (unsigned short*)p;  p += BIG * 2;       // reused as g
    unsigned short* xb_bf  = (unsigned short*)p;  p += BIG * 2;
    unsigned short* z_bf   = (unsigned short*)p;  p += BIG * 2;
    unsigned short* xact_bf= (unsigned short*)p;  p += BIG * 2;
    unsigned short* t_bf   = (unsigned short*)p;  p += (size_t)MM * 128 * 2;
    unsigned short* dBC    = (unsigned short*)p;  p += (size_t)MM * 3072 * 2;
    float* tpart = (float*)p;                     p += (size_t)4 * MM * 128 * 4;
    float* P     = (float*)p;                     p += (size_t)BB * NC * DD * 4;
    float* Hc    = (float*)p;                     p += (size_t)BB * NC * DD * 4;
    float* hin   = (float*)p;                     p += (size_t)BB * NC * DD * 4;
    unsigned short* WinT  = (unsigned short*)p;   p += (size_t)2 * DD * DD * 2;
    unsigned short* WoutT = (unsigned short*)p;   p += (size_t)DD * DD * 2;
    unsigned short* WgT   = (unsigned short*)p;   p += (size_t)128 * DD * 2;
    unsigned short* WupT  = (unsigned short*)p;   p += (size_t)3072 * 128 * 2;
    unsigned short* g_bf  = xn_bf;

    {
        void (*k1)(const unsigned short*, const unsigned short*, void*, void*,
                   const float*, int, int, int) = gemm256<1>;
        void (*k2)(const unsigned short*, const unsigned short*, void*, void*,
                   const float*, int, int, int) = gemm256<2>;
        (void)hipFuncSetAttribute((const void*)k1,
            hipFuncAttributeMaxDynamicSharedMemorySize, 131072);
        (void)hipFuncSetAttribute((const void*)k2,
            hipFuncAttributeMaxDynamicSharedMemorySize, 131072);
    }

    // 0. weight prep
    transpose_bf16<<<dim3(2 * DD / 32, DD / 32), 256, 0, stream>>>(W_in, WinT, DD, 2 * DD);
    transpose_bf16<<<dim3(DD / 32, DD / 32), 256, 0, stream>>>(W_out, WoutT, DD, DD);
    build_wg<<<(128 * DD) / 256, 256, 0, stream>>>(W_xp, W_Bg, W_Cg, WgT);
    build_wup<<<(3072 * 128) / 256, 256, 0, stream>>>(W_dt, W_Bp, W_Cp, WupT);
    // 1. LayerNorm
    ln_kernel<<<MM, 256, 0, stream>>>(x, gamma, beta, xn_bf);
    // 2. in_proj -> xb | z (bf16), 256^2 pipelined
    gemm256<1><<<dim3(2 * DD / 256, MM / 256), 512, 131072, stream>>>(
        xn_bf, WinT, xb_bf, z_bf, nullptr, MM, 2 * DD, DD);
    // 3. depthwise conv + SiLU
    conv_silu<<<(MM * DD / 8) / 256, 256, 0, stream>>>(xb_bf, conv_w, conv_b, xact_bf);
    // 4a. down-proj (split-K=4) + reduce -> t (M x 128 bf16)
    gemm_mfma<3><<<dim3(1, MM / 128, 4), 256, 0, stream>>>(
        xact_bf, WgT, tpart, nullptr, nullptr, MM, 128, DD);
    reduce_t<<<(MM * 128 / 4) / 256, 256, 0, stream>>>(tpart, t_bf);
    // 4b. up-proj -> dBC = [softplus'd delta | Bm | Cm] (M x 3072 bf16)
    gemm_mfma<4><<<dim3(3072 / 128, MM / 128), 256, 0, stream>>>(
        t_bf, WupT, dBC, nullptr, b_dt, MM, 3072, 128);
    // 5. chunked selective scan + gating
    scan_p1<<<dim3(DD / 512, NC, BB), 256, 0, stream>>>(dBC, xact_bf, A, P, Hc);
    scan_p2<<<dim3(DD / 256, BB), 256, 0, stream>>>(P, Hc, hin);
    scan_p3<<<dim3(DD / 512, NC, BB), 256, 0, stream>>>(dBC, xact_bf, z_bf, hin,
                                                        A, Dsk, g_bf);
    // 6. out_proj + residual (f32 out), 256^2 pipelined
    gemm256<2><<<dim3(DD / 256, MM / 256), 512, 131072, stream>>>(
        g_bf, WoutT, out, nullptr, x, MM, DD, DD);
}